// Round 1
// baseline (545.354 us; speedup 1.0000x reference)
//
#include <hip/hip_runtime.h>
#include <hip/hip_bf16.h>
#include <stdint.h>

#define SEQ 2048
#define HIDDEN 4096
#define NHEADS 32
#define HD 128
#define QKV_LD 6144
#define OUT_LD 4096

typedef __attribute__((ext_vector_type(8))) short short8;
typedef __attribute__((ext_vector_type(4))) short short4v;
typedef __attribute__((ext_vector_type(4))) float f32x4;
typedef __attribute__((ext_vector_type(4))) int int4v;
typedef __attribute__((ext_vector_type(4))) float float4v;

__device__ __forceinline__ short f2bf(float f) {
  uint32_t u = __builtin_bit_cast(uint32_t, f);
  u += 0x7fff + ((u >> 16) & 1);   // RNE
  return (short)(u >> 16);
}

// ---------------- cast fp32 -> bf16 ----------------
__global__ void cast_kernel(const float* __restrict__ in, short* __restrict__ out, int n4) {
  int stride = gridDim.x * blockDim.x;
  for (int i = blockIdx.x * blockDim.x + threadIdx.x; i < n4; i += stride) {
    float4v v = ((const float4v*)in)[i];
    short4v o;
    o[0] = f2bf(v[0]); o[1] = f2bf(v[1]); o[2] = f2bf(v[2]); o[3] = f2bf(v[3]);
    ((short4v*)out)[i] = o;
  }
}

// ---------------- GEMM: C[M][N] = A[M][K] * B[N][K]^T (m97 structure) ----------------
template <typename OT>
__global__ __launch_bounds__(256) void gemm_bt(const short* __restrict__ A,
                                               const short* __restrict__ B,
                                               OT* __restrict__ C,
                                               int M, int N, int K) {
  __shared__ __align__(16) short As[128 * 32];
  __shared__ __align__(16) short Bs[128 * 32];
  const int tid = threadIdx.x;
  const int wave = tid >> 6, lane = tid & 63;
  const int lhi = lane >> 4, llo = lane & 15;
  const int wm = wave >> 1, wn = wave & 1;
  const size_t arow0 = (size_t)blockIdx.x * 128;
  const size_t brow0 = (size_t)blockIdx.y * 128;
  const int srow = lane >> 2, schunk = lane & 3;  // staging: 16 rows x 4 chunks per 1KB call

  f32x4 acc[4][4] = {};

  const short* aB = A + arow0 * K;
  const short* bB = B + brow0 * K;

  for (int k0 = 0; k0 < K; k0 += 32) {
    __syncthreads();  // previous tile fully consumed
#pragma unroll
    for (int c = 0; c < 2; c++) {
      const int call = wave + c * 4;      // 8 calls cover 128 rows x 32 cols (8KB)
      const int row = call * 16 + srow;
      __builtin_amdgcn_global_load_lds(
          (const __attribute__((address_space(1))) uint32_t*)(aB + (size_t)row * K + k0 + schunk * 8),
          (__attribute__((address_space(3))) uint32_t*)(As + call * 512), 16, 0, 0);
      __builtin_amdgcn_global_load_lds(
          (const __attribute__((address_space(1))) uint32_t*)(bB + (size_t)row * K + k0 + schunk * 8),
          (__attribute__((address_space(3))) uint32_t*)(Bs + call * 512), 16, 0, 0);
    }
    __syncthreads();  // staging complete (vmcnt drained by syncthreads)

    short8 af[4], bf[4];
#pragma unroll
    for (int i = 0; i < 4; i++) {
      af[i] = *(const short8*)(As + (wm * 64 + i * 16 + llo) * 32 + lhi * 8);
      bf[i] = *(const short8*)(Bs + (wn * 64 + i * 16 + llo) * 32 + lhi * 8);
    }
#pragma unroll
    for (int i = 0; i < 4; i++)
#pragma unroll
      for (int j = 0; j < 4; j++)
        acc[i][j] = __builtin_amdgcn_mfma_f32_16x16x32_bf16(af[i], bf[j], acc[i][j], 0, 0, 0);
  }

#pragma unroll
  for (int i = 0; i < 4; i++)
#pragma unroll
    for (int j = 0; j < 4; j++)
#pragma unroll
      for (int r = 0; r < 4; r++) {
        size_t row = arow0 + wm * 64 + i * 16 + lhi * 4 + r;
        size_t col = brow0 + wn * 64 + j * 16 + llo;
        float v = acc[i][j][r];
        if constexpr (sizeof(OT) == 2) C[row * N + col] = f2bf(v);
        else                           C[row * N + col] = v;
      }
}

// ---------------- flash attention, causal GQA ----------------
// grid: (SEQ/64, NHEADS); block 256 = 4 waves x 16 q-rows
__global__ __launch_bounds__(256) void attn_fwd(const short* __restrict__ qkv,
                                                short* __restrict__ aout) {
  const int qt = blockIdx.x;
  const int h = blockIdx.y;
  const int kvh = h >> 2, g = h & 3;
  const int tid = threadIdx.x;
  const int wave = tid >> 6, lane = tid & 63;
  const int lhi = lane >> 4, llo = lane & 15;

  __shared__ __align__(16) short Ksm[64 * 128];      // XOR-swizzled (chunk ^= row&7)
  __shared__ __align__(16) short Vsm[64 * 130];      // row-major, +2 pad
  __shared__ __align__(16) short Psm[4][16 * 80];    // per-wave P tile, stride 80

  const float scale = 0.08838834764831845f;  // 1/sqrt(128)

  // Q fragments held in registers for the whole kernel
  const int qrow = qt * 64 + wave * 16 + llo;
  const short* qbase = qkv + (size_t)qrow * QKV_LD + (kvh * 6 + g) * HD;
  short8 qf[4];
#pragma unroll
  for (int kk = 0; kk < 4; kk++) qf[kk] = *(const short8*)(qbase + kk * 32 + lhi * 8);

  f32x4 o[8] = {};
  float mrow[4], lrow[4];
#pragma unroll
  for (int r = 0; r < 4; r++) { mrow[r] = -1e30f; lrow[r] = 0.f; }

  const short* Kg = qkv + (kvh * 6 + 4) * HD;
  const short* Vg = qkv + (kvh * 6 + 5) * HD;

  const int ntiles = qt + 1;
  for (int t = 0; t < ntiles; t++) {
    __syncthreads();  // previous tile's K/V fully consumed
    // K tile: 64x128 via global_load_lds, source pre-swizzled so reads are conflict-free
#pragma unroll
    for (int c = 0; c < 4; c++) {
      const int call = wave * 4 + c;     // 1KB per call = 4 rows of 256B
      const int row = call * 4 + lhi;
      const int sc = llo ^ (row & 7);
      __builtin_amdgcn_global_load_lds(
          (const __attribute__((address_space(1))) uint32_t*)(Kg + (size_t)(t * 64 + row) * QKV_LD + sc * 8),
          (__attribute__((address_space(3))) uint32_t*)(Ksm + call * 512), 16, 0, 0);
    }
    // V tile: register-staged into padded row-major
#pragma unroll
    for (int c = 0; c < 4; c++) {
      const int idx = c * 256 + tid;
      const int vr = idx >> 4, vc = idx & 15;
      short8 v = *(const short8*)(Vg + (size_t)(t * 64 + vr) * QKV_LD + vc * 8);
      int4v iv = __builtin_bit_cast(int4v, v);
      int* dst = (int*)(Vsm + vr * 130 + vc * 8);
      dst[0] = iv[0]; dst[1] = iv[1]; dst[2] = iv[2]; dst[3] = iv[3];
    }
    __syncthreads();

    // S = Q K^T
    f32x4 s[4] = {};
#pragma unroll
    for (int n = 0; n < 4; n++) {
#pragma unroll
      for (int kk = 0; kk < 4; kk++) {
        const int krow = n * 16 + llo;
        const int ch = (kk * 4 + lhi) ^ (krow & 7);
        short8 kf = *(const short8*)(Ksm + krow * 128 + ch * 8);
        s[n] = __builtin_amdgcn_mfma_f32_16x16x32_bf16(qf[kk], kf, s[n], 0, 0, 0);
      }
    }

    // scale + causal mask (C layout: local q row = lhi*4+r, kv col = n*16+llo)
    float sv[4][4];
    const bool diag = (t == qt);
#pragma unroll
    for (int n = 0; n < 4; n++)
#pragma unroll
      for (int r = 0; r < 4; r++) {
        float x = s[n][r] * scale;
        if (diag && (n * 16 + llo > wave * 16 + lhi * 4 + r)) x = -1e30f;
        sv[n][r] = x;
      }

    // online softmax (16-lane groups share a row)
    float alpha[4];
#pragma unroll
    for (int r = 0; r < 4; r++) {
      float rm = fmaxf(fmaxf(sv[0][r], sv[1][r]), fmaxf(sv[2][r], sv[3][r]));
#pragma unroll
      for (int msk = 1; msk < 16; msk <<= 1) rm = fmaxf(rm, __shfl_xor(rm, msk));
      const float mnew = fmaxf(mrow[r], rm);
      alpha[r] = __expf(mrow[r] - mnew);
      mrow[r] = mnew;
      float rs = 0.f;
#pragma unroll
      for (int n = 0; n < 4; n++) {
        float p = __expf(sv[n][r] - mnew);
        sv[n][r] = p;
        rs += p;
      }
#pragma unroll
      for (int msk = 1; msk < 16; msk <<= 1) rs += __shfl_xor(rs, msk);
      lrow[r] = lrow[r] * alpha[r] + rs;
    }
#pragma unroll
    for (int nn = 0; nn < 8; nn++)
#pragma unroll
      for (int r = 0; r < 4; r++) o[nn][r] *= alpha[r];

    // P -> LDS (bf16), then PV
    short* P = &Psm[wave][0];
#pragma unroll
    for (int n = 0; n < 4; n++)
#pragma unroll
      for (int r = 0; r < 4; r++)
        P[(lhi * 4 + r) * 80 + n * 16 + llo] = f2bf(sv[n][r]);

#pragma unroll
    for (int ks = 0; ks < 2; ks++) {
      short8 pa = *(const short8*)(P + llo * 80 + ks * 32 + lhi * 8);
#pragma unroll
      for (int nn = 0; nn < 8; nn++) {
        short8 vb;
#pragma unroll
        for (int i = 0; i < 8; i++)
          vb[i] = Vsm[(ks * 32 + lhi * 8 + i) * 130 + nn * 16 + llo];
        o[nn] = __builtin_amdgcn_mfma_f32_16x16x32_bf16(pa, vb, o[nn], 0, 0, 0);
      }
    }
  }

  // epilogue: normalize and store bf16 [s][h*128+d]
#pragma unroll
  for (int nn = 0; nn < 8; nn++)
#pragma unroll
    for (int r = 0; r < 4; r++) {
      const size_t row = qt * 64 + wave * 16 + lhi * 4 + r;
      const size_t col = (size_t)h * HD + nn * 16 + llo;
      aout[row * OUT_LD + col] = f2bf(o[nn][r] / lrow[r]);
    }
}

// ---------------- launch ----------------
extern "C" void kernel_launch(void* const* d_in, const int* in_sizes, int n_in,
                              void* d_out, int out_size, void* d_ws, size_t ws_size,
                              hipStream_t stream) {
  const float* tokens = (const float*)d_in[0];  // [2048,1,4096]
  const float* wqkv   = (const float*)d_in[1];  // [6144,4096]
  const float* wproj  = (const float*)d_in[2];  // [4096,4096]
  float* out = (float*)d_out;                   // [2048,1,4096] fp32

  short* tok_bf   = (short*)d_ws;                        // 2048*4096
  short* wqkv_bf  = tok_bf   + (size_t)SEQ * HIDDEN;     // 6144*4096
  short* wproj_bf = wqkv_bf  + (size_t)QKV_LD * HIDDEN;  // 4096*4096
  short* qkv_bf   = wproj_bf + (size_t)HIDDEN * OUT_LD;  // 2048*6144
  short* attn_bf  = qkv_bf   + (size_t)SEQ * QKV_LD;     // 2048*4096
  // total ws use: ~143 MB

  cast_kernel<<<2048, 256, 0, stream>>>(tokens, tok_bf, SEQ * HIDDEN / 4);
  cast_kernel<<<2048, 256, 0, stream>>>(wqkv, wqkv_bf, QKV_LD * HIDDEN / 4);
  cast_kernel<<<2048, 256, 0, stream>>>(wproj, wproj_bf, HIDDEN * OUT_LD / 4);

  gemm_bt<short><<<dim3(SEQ / 128, QKV_LD / 128), 256, 0, stream>>>(
      tok_bf, wqkv_bf, qkv_bf, SEQ, QKV_LD, HIDDEN);

  attn_fwd<<<dim3(SEQ / 64, NHEADS), 256, 0, stream>>>(qkv_bf, attn_bf);

  gemm_bt<float><<<dim3(SEQ / 128, OUT_LD / 128), 256, 0, stream>>>(
      attn_bf, wproj_bf, out, SEQ, OUT_LD, HIDDEN);
}

// Round 3
// 417.923 us; speedup vs baseline: 1.3049x; 1.3049x over previous
//
#include <hip/hip_runtime.h>
#include <hip/hip_bf16.h>
#include <stdint.h>

#define SEQ 2048
#define HIDDEN 4096
#define NHEADS 32
#define HD 128
#define QKV_LD 6144
#define OUT_LD 4096

typedef __attribute__((ext_vector_type(8))) short short8;
typedef __attribute__((ext_vector_type(4))) short short4v;
typedef __attribute__((ext_vector_type(4))) float f32x4;
typedef __attribute__((ext_vector_type(4))) int int4v;
typedef __attribute__((ext_vector_type(2))) unsigned int uint2v;
typedef __attribute__((ext_vector_type(4))) float float4v;

__device__ __forceinline__ short f2bf(float f) {
  uint32_t u = __builtin_bit_cast(uint32_t, f);
  u += 0x7fff + ((u >> 16) & 1);   // RNE
  return (short)(u >> 16);
}

// ---------------- cast fp32 -> bf16 ----------------
__global__ void cast_kernel(const float* __restrict__ in, short* __restrict__ out, int n4) {
  int stride = gridDim.x * blockDim.x;
  for (int i = blockIdx.x * blockDim.x + threadIdx.x; i < n4; i += stride) {
    float4v v = ((const float4v*)in)[i];
    short4v o;
    o[0] = f2bf(v[0]); o[1] = f2bf(v[1]); o[2] = f2bf(v[2]); o[3] = f2bf(v[3]);
    ((short4v*)out)[i] = o;
  }
}

// ---------------- GEMM: C[M][N] = A[M][K] * B[N][K]^T (m97 structure) ----------------
template <typename OT>
__global__ __launch_bounds__(256) void gemm_bt(const short* __restrict__ A,
                                               const short* __restrict__ B,
                                               OT* __restrict__ C,
                                               int M, int N, int K) {
  __shared__ __align__(16) short As[128 * 32];
  __shared__ __align__(16) short Bs[128 * 32];
  const int tid = threadIdx.x;
  const int wave = tid >> 6, lane = tid & 63;
  const int lhi = lane >> 4, llo = lane & 15;
  const int wm = wave >> 1, wn = wave & 1;
  const size_t arow0 = (size_t)blockIdx.x * 128;
  const size_t brow0 = (size_t)blockIdx.y * 128;
  const int srow = lane >> 2, schunk = lane & 3;

  f32x4 acc[4][4] = {};

  const short* aB = A + arow0 * K;
  const short* bB = B + brow0 * K;

  for (int k0 = 0; k0 < K; k0 += 32) {
    __syncthreads();
#pragma unroll
    for (int c = 0; c < 2; c++) {
      const int call = wave + c * 4;
      const int row = call * 16 + srow;
      __builtin_amdgcn_global_load_lds(
          (const __attribute__((address_space(1))) uint32_t*)(aB + (size_t)row * K + k0 + schunk * 8),
          (__attribute__((address_space(3))) uint32_t*)(As + call * 512), 16, 0, 0);
      __builtin_amdgcn_global_load_lds(
          (const __attribute__((address_space(1))) uint32_t*)(bB + (size_t)row * K + k0 + schunk * 8),
          (__attribute__((address_space(3))) uint32_t*)(Bs + call * 512), 16, 0, 0);
    }
    __syncthreads();

    short8 af[4], bf[4];
#pragma unroll
    for (int i = 0; i < 4; i++) {
      af[i] = *(const short8*)(As + (wm * 64 + i * 16 + llo) * 32 + lhi * 8);
      bf[i] = *(const short8*)(Bs + (wn * 64 + i * 16 + llo) * 32 + lhi * 8);
    }
#pragma unroll
    for (int i = 0; i < 4; i++)
#pragma unroll
      for (int j = 0; j < 4; j++)
        acc[i][j] = __builtin_amdgcn_mfma_f32_16x16x32_bf16(af[i], bf[j], acc[i][j], 0, 0, 0);
  }

#pragma unroll
  for (int i = 0; i < 4; i++)
#pragma unroll
    for (int j = 0; j < 4; j++)
#pragma unroll
      for (int r = 0; r < 4; r++) {
        size_t row = arow0 + wm * 64 + i * 16 + lhi * 4 + r;
        size_t col = brow0 + wn * 64 + j * 16 + llo;
        float v = acc[i][j][r];
        if constexpr (sizeof(OT) == 2) C[row * N + col] = f2bf(v);
        else                           C[row * N + col] = v;
      }
}

// ---------------- flash attention, causal GQA ----------------
// grid: (NHEADS, SEQ/64); block 256 = 4 waves x 16 q-rows
// qt reversed so heavy (long-causal) blocks dispatch first.
__global__ __launch_bounds__(256, 3) void attn_fwd(const short* __restrict__ qkv,
                                                   short* __restrict__ aout) {
  const int qt = gridDim.y - 1 - blockIdx.y;
  const int h = blockIdx.x;
  const int kvh = h >> 2, g = h & 3;
  const int tid = threadIdx.x;
  const int wave = tid >> 6, lane = tid & 63;
  const int lhi = lane >> 4, llo = lane & 15;

  __shared__ __align__(16) short Ksm[64 * 128];      // XOR-swizzled (chunk ^= row&7)
  __shared__ __align__(16) short Vsm[64 * 128];      // subtiled [k/4][d/16][4][16] for tr_b16 reads
  __shared__ __align__(16) short Psm[4][16 * 72];    // per-wave P tile, stride 72

  const float scale = 0.08838834764831845f;  // 1/sqrt(128)

  // Q fragments held in registers for the whole kernel
  const int qrow = qt * 64 + wave * 16 + llo;
  const short* qbase = qkv + (size_t)qrow * QKV_LD + (kvh * 6 + g) * HD;
  short8 qf[4];
#pragma unroll
  for (int kk = 0; kk < 4; kk++) qf[kk] = *(const short8*)(qbase + kk * 32 + lhi * 8);

  f32x4 o[8] = {};
  float mrow[4], lrow[4];
#pragma unroll
  for (int r = 0; r < 4; r++) { mrow[r] = -1e30f; lrow[r] = 0.f; }

  const short* Kg = qkv + (kvh * 6 + 4) * HD;
  const short* Vg = qkv + (kvh * 6 + 5) * HD;

  // per-lane LDS byte address base for V cooperative transpose-reads:
  // lane llo supplies the address of ITS 8-byte chunk of the group's 128B subtile;
  // group lhi targets subtile (k-block = lhi*2 (+hh) within ks-slab).
  const uint32_t vlane = (uint32_t)(uintptr_t)(__attribute__((address_space(3))) short*)Vsm
                         + (uint32_t)(lhi * 2048 + llo * 8);

  const int ntiles = qt + 1;
  for (int t = 0; t < ntiles; t++) {
    __syncthreads();  // previous tile's K/V fully consumed
    // K tile: 64x128 via global_load_lds, source pre-swizzled so reads are conflict-free
#pragma unroll
    for (int c = 0; c < 4; c++) {
      const int call = wave * 4 + c;
      const int row = call * 4 + lhi;
      const int sc = llo ^ (row & 7);
      __builtin_amdgcn_global_load_lds(
          (const __attribute__((address_space(1))) uint32_t*)(Kg + (size_t)(t * 64 + row) * QKV_LD + sc * 8),
          (__attribute__((address_space(3))) uint32_t*)(Ksm + call * 512), 16, 0, 0);
    }
    // V tile: register-staged into subtiled layout [k>>2][d>>4][k&3][d&15]
    // each short8 (one k, 8 consecutive d) is contiguous in one subtile row -> ds_write_b128
#pragma unroll
    for (int c = 0; c < 4; c++) {
      const int idx = c * 256 + tid;
      const int vr = idx >> 4, vc = idx & 15;
      short8 v = *(const short8*)(Vg + (size_t)(t * 64 + vr) * QKV_LD + vc * 8);
      *(short8*)(Vsm + ((vr >> 2) * 8 + (vc >> 1)) * 64 + (vr & 3) * 16 + (vc & 1) * 8) = v;
    }
    __syncthreads();

    // S = Q K^T
    f32x4 s[4] = {};
#pragma unroll
    for (int n = 0; n < 4; n++) {
#pragma unroll
      for (int kk = 0; kk < 4; kk++) {
        const int krow = n * 16 + llo;
        const int ch = (kk * 4 + lhi) ^ (krow & 7);
        short8 kf = *(const short8*)(Ksm + krow * 128 + ch * 8);
        s[n] = __builtin_amdgcn_mfma_f32_16x16x32_bf16(qf[kk], kf, s[n], 0, 0, 0);
      }
    }

    // scale + causal mask (C layout: local q row = lhi*4+r, kv col = n*16+llo)
    float sv[4][4];
    const bool diag = (t == qt);
#pragma unroll
    for (int n = 0; n < 4; n++)
#pragma unroll
      for (int r = 0; r < 4; r++) {
        float x = s[n][r] * scale;
        if (diag && (n * 16 + llo > wave * 16 + lhi * 4 + r)) x = -1e30f;
        sv[n][r] = x;
      }

    // online softmax (16-lane groups share a row)
    float alpha[4];
#pragma unroll
    for (int r = 0; r < 4; r++) {
      float rm = fmaxf(fmaxf(sv[0][r], sv[1][r]), fmaxf(sv[2][r], sv[3][r]));
#pragma unroll
      for (int msk = 1; msk < 16; msk <<= 1) rm = fmaxf(rm, __shfl_xor(rm, msk));
      const float mnew = fmaxf(mrow[r], rm);
      alpha[r] = __expf(mrow[r] - mnew);
      mrow[r] = mnew;
      float rs = 0.f;
#pragma unroll
      for (int n = 0; n < 4; n++) {
        float p = __expf(sv[n][r] - mnew);
        sv[n][r] = p;
        rs += p;
      }
#pragma unroll
      for (int msk = 1; msk < 16; msk <<= 1) rs += __shfl_xor(rs, msk);
      lrow[r] = lrow[r] * alpha[r] + rs;
    }
#pragma unroll
    for (int nn = 0; nn < 8; nn++)
#pragma unroll
      for (int r = 0; r < 4; r++) o[nn][r] *= alpha[r];

    // P -> LDS (bf16)
    short* P = &Psm[wave][0];
#pragma unroll
    for (int n = 0; n < 4; n++)
#pragma unroll
      for (int r = 0; r < 4; r++)
        P[(lhi * 4 + r) * 72 + n * 16 + llo] = f2bf(sv[n][r]);

    // PV: A-frag from Psm, B-frags via cooperative hardware transpose reads of subtiled Vsm
    short8 pa0 = *(const short8*)(P + llo * 72 + lhi * 8);
    short8 pa1 = *(const short8*)(P + llo * 72 + 32 + lhi * 8);
#pragma unroll
    for (int ks = 0; ks < 2; ks++) {
      uint2v vr_[8][2];
#pragma unroll
      for (int nn = 0; nn < 8; nn++)
#pragma unroll
        for (int hh = 0; hh < 2; hh++) {
          uint32_t a = vlane + (uint32_t)(ks * 8192 + hh * 1024 + nn * 128);
          asm volatile("ds_read_b64_tr_b16 %0, %1" : "=v"(vr_[nn][hh]) : "v"(a));
        }
      asm volatile("s_waitcnt lgkmcnt(0)" ::: "memory");
      __builtin_amdgcn_sched_barrier(0);
      const short8 pa = ks ? pa1 : pa0;
#pragma unroll
      for (int nn = 0; nn < 8; nn++) {
        int4v tv;
        tv[0] = (int)vr_[nn][0][0]; tv[1] = (int)vr_[nn][0][1];
        tv[2] = (int)vr_[nn][1][0]; tv[3] = (int)vr_[nn][1][1];
        o[nn] = __builtin_amdgcn_mfma_f32_16x16x32_bf16(pa, __builtin_bit_cast(short8, tv), o[nn], 0, 0, 0);
      }
    }
  }

  // epilogue: normalize and store bf16 [s][h*128+d]
#pragma unroll
  for (int nn = 0; nn < 8; nn++)
#pragma unroll
    for (int r = 0; r < 4; r++) {
      const size_t row = qt * 64 + wave * 16 + lhi * 4 + r;
      const size_t col = (size_t)h * HD + nn * 16 + llo;
      aout[row * OUT_LD + col] = f2bf(o[nn][r] / lrow[r]);
    }
}

// ---------------- launch ----------------
extern "C" void kernel_launch(void* const* d_in, const int* in_sizes, int n_in,
                              void* d_out, int out_size, void* d_ws, size_t ws_size,
                              hipStream_t stream) {
  const float* tokens = (const float*)d_in[0];  // [2048,1,4096]
  const float* wqkv   = (const float*)d_in[1];  // [6144,4096]
  const float* wproj  = (const float*)d_in[2];  // [4096,4096]
  float* out = (float*)d_out;                   // [2048,1,4096] fp32

  short* tok_bf   = (short*)d_ws;                        // 2048*4096
  short* wqkv_bf  = tok_bf   + (size_t)SEQ * HIDDEN;     // 6144*4096
  short* wproj_bf = wqkv_bf  + (size_t)QKV_LD * HIDDEN;  // 4096*4096
  short* qkv_bf   = wproj_bf + (size_t)HIDDEN * OUT_LD;  // 2048*6144
  short* attn_bf  = qkv_bf   + (size_t)SEQ * QKV_LD;     // 2048*4096

  cast_kernel<<<2048, 256, 0, stream>>>(tokens, tok_bf, SEQ * HIDDEN / 4);
  cast_kernel<<<2048, 256, 0, stream>>>(wqkv, wqkv_bf, QKV_LD * HIDDEN / 4);
  cast_kernel<<<2048, 256, 0, stream>>>(wproj, wproj_bf, HIDDEN * OUT_LD / 4);

  gemm_bt<short><<<dim3(SEQ / 128, QKV_LD / 128), 256, 0, stream>>>(
      tok_bf, wqkv_bf, qkv_bf, SEQ, QKV_LD, HIDDEN);

  attn_fwd<<<dim3(NHEADS, SEQ / 64), 256, 0, stream>>>(qkv_bf, attn_bf);

  gemm_bt<float><<<dim3(SEQ / 128, OUT_LD / 128), 256, 0, stream>>>(
      attn_bf, wproj_bf, out, SEQ, OUT_LD, HIDDEN);
}

// Round 4
// 400.538 us; speedup vs baseline: 1.3616x; 1.0434x over previous
//
#include <hip/hip_runtime.h>
#include <hip/hip_bf16.h>
#include <stdint.h>

#define SEQ 2048
#define HIDDEN 4096
#define NHEADS 32
#define HD 128
#define QKV_LD 6144
#define OUT_LD 4096

typedef __attribute__((ext_vector_type(8))) short short8;
typedef __attribute__((ext_vector_type(4))) short short4v;
typedef __attribute__((ext_vector_type(4))) float f32x4;
typedef __attribute__((ext_vector_type(4))) int int4v;
typedef __attribute__((ext_vector_type(2))) unsigned int uint2v;
typedef __attribute__((ext_vector_type(4))) float float4v;

__device__ __forceinline__ short f2bf(float f) {
  uint32_t u = __builtin_bit_cast(uint32_t, f);
  u += 0x7fff + ((u >> 16) & 1);   // RNE
  return (short)(u >> 16);
}

// ---------------- cast fp32 -> bf16 ----------------
__global__ void cast_kernel(const float* __restrict__ in, short* __restrict__ out, int n4) {
  int stride = gridDim.x * blockDim.x;
  for (int i = blockIdx.x * blockDim.x + threadIdx.x; i < n4; i += stride) {
    float4v v = ((const float4v*)in)[i];
    short4v o;
    o[0] = f2bf(v[0]); o[1] = f2bf(v[1]); o[2] = f2bf(v[2]); o[3] = f2bf(v[3]);
    ((short4v*)out)[i] = o;
  }
}

// ============ 256x256 8-phase GEMM: C[M][N] = A[M][K] * B[N][K]^T ============
// 512 thr = 8 waves (2M x 4N), BK=64, double-buffered 128KB LDS,
// counted-vmcnt pipeline, chunk^=row&7 LDS swizzle, setprio MFMA clusters.
template <typename OT>
__global__ __launch_bounds__(512, 2) void gemm256(const short* __restrict__ A,
                                                  const short* __restrict__ B,
                                                  OT* __restrict__ C,
                                                  int M, int N, int K, int NT) {
  __shared__ __align__(16) short lds[65536];  // A: [0,32K) shorts, B: [32K,64K); per side 2 bufs x 16384
  const int tid = threadIdx.x;
  const int w = tid >> 6, lane = tid & 63;
  const int wr = w >> 2, wc = w & 3;
  const int llo = lane & 15, lhi = lane >> 4;

  // T1 bijective XCD swizzle (nwg % 8 == 0): XCD gets contiguous work chunk
  const int nwg = gridDim.x;
  const int cpx = nwg >> 3;
  const int work = ((int)blockIdx.x & 7) * cpx + ((int)blockIdx.x >> 3);
  const int mt = work / NT, nt = work % NT;
  const size_t arow0 = (size_t)mt * 256, brow0 = (size_t)nt * 256;
  const short* Ab = A + arow0 * K;
  const short* Bb = B + brow0 * K;

  const int s_r = lane >> 3;   // staging: row within 8-row slice
  const int s_c = lane & 7;    // staging: 16B chunk (of 8 per 128B row)

  const int NKT = K >> 6;      // K-tiles of 64
  const int GMAX = NKT << 2;   // half-tiles total

  f32x4 acc[8][4] = {};
  short8 af[4][2], bf[4][2];

  // stage half-tile g (tile g>>2, ht g&3: 0=A lo,1=A hi,2=B lo,3=B hi); 2 loads/thread
  auto STAGE = [&](int g) {
    if (g >= GMAX) return;
    const int kt = g >> 2, h = g & 3;
    const int bufd = kt & 1;
    const int side = h >> 1;
    const int htrow = (h & 1) << 7;
    const short* gb = side ? Bb : Ab;
#pragma unroll
    for (int c = 0; c < 2; c++) {
      const int slice = (c << 3) + w;              // 0..15
      const int rowrel = htrow + (slice << 3) + s_r;
      const short* src = gb + (size_t)rowrel * K + (kt << 6) + ((s_c ^ (rowrel & 7)) << 3);
      short* dst = lds + (side << 15) + (bufd << 14) + htrow * 64 + (slice << 9);
      __builtin_amdgcn_global_load_lds(
          (const __attribute__((address_space(1))) uint32_t*)src,
          (__attribute__((address_space(3))) uint32_t*)dst, 16, 0, 0);
    }
  };

  auto LDA = [&](int bufd, int m, int kk) -> short8 {
    const int row = (wr << 7) + (m << 4) + llo;
    const int ch = ((kk << 2) + lhi) ^ (row & 7);
    return *(const short8*)(lds + (bufd << 14) + row * 64 + (ch << 3));
  };
  auto LDB = [&](int bufd, int n, int kk) -> short8 {
    const int row = (wc << 6) + (n << 4) + llo;
    const int ch = ((kk << 2) + lhi) ^ (row & 7);
    return *(const short8*)(lds + 32768 + (bufd << 14) + row * 64 + (ch << 3));
  };
  auto QUAD = [&](int mh, int nh) {
    __builtin_amdgcn_s_setprio(1);
#pragma unroll
    for (int mi = 0; mi < 4; mi++)
#pragma unroll
      for (int ni = 0; ni < 2; ni++)
#pragma unroll
        for (int kk = 0; kk < 2; kk++)
          acc[(mh << 2) + mi][(nh << 1) + ni] = __builtin_amdgcn_mfma_f32_16x16x32_bf16(
              af[mi][kk], bf[(nh << 1) + ni][kk], acc[(mh << 2) + mi][(nh << 1) + ni], 0, 0, 0);
    __builtin_amdgcn_s_setprio(0);
  };

  // ---- prologue: tiles 0 (buf0) and 1 (buf1); gate tile0 ----
#pragma unroll
  for (int g0 = 0; g0 < 8; g0++) STAGE(g0);
  asm volatile("s_waitcnt vmcnt(8)" ::: "memory");
  __builtin_amdgcn_s_barrier();

  int g = 5;  // iter0 ph0-2 re-stage tile1 ht1-3 (same data, benign) -> uniform schedule
  const int NIT = NKT >> 1;
  for (int it = 0; it < NIT; ++it) {
    // ---- phase 0: buf0 quad(0,0); reads af[m0-3], bf[n0-1] ----
#pragma unroll
    for (int mi = 0; mi < 4; mi++) { af[mi][0] = LDA(0, mi, 0); af[mi][1] = LDA(0, mi, 1); }
#pragma unroll
    for (int ni = 0; ni < 2; ni++) { bf[ni][0] = LDB(0, ni, 0); bf[ni][1] = LDB(0, ni, 1); }
    STAGE(g++);
    __builtin_amdgcn_s_barrier();
    asm volatile("s_waitcnt lgkmcnt(0)" ::: "memory");
    __builtin_amdgcn_sched_barrier(0);
    QUAD(0, 0);
    __builtin_amdgcn_s_barrier();
    // ---- phase 1: buf0 quad(0,1); reads bf[n2-3] ----
#pragma unroll
    for (int ni = 0; ni < 2; ni++) { bf[2 + ni][0] = LDB(0, 2 + ni, 0); bf[2 + ni][1] = LDB(0, 2 + ni, 1); }
    STAGE(g++);
    __builtin_amdgcn_s_barrier();
    asm volatile("s_waitcnt lgkmcnt(0)" ::: "memory");
    __builtin_amdgcn_sched_barrier(0);
    QUAD(0, 1);
    __builtin_amdgcn_s_barrier();
    // ---- phase 2: buf0 quad(1,0); reads af[m4-7] (buf0 fully reg-consumed after this) ----
#pragma unroll
    for (int mi = 0; mi < 4; mi++) { af[mi][0] = LDA(0, 4 + mi, 0); af[mi][1] = LDA(0, 4 + mi, 1); }
    STAGE(g++);
    __builtin_amdgcn_s_barrier();
    asm volatile("s_waitcnt lgkmcnt(0)" ::: "memory");
    __builtin_amdgcn_sched_barrier(0);
    QUAD(1, 0);
    __builtin_amdgcn_s_barrier();
    // ---- phase 3: buf0 quad(1,1); stage may now overwrite buf0; gate buf1 before ph4 ----
    {
      const bool st = (g < GMAX);
      STAGE(g++);
      __builtin_amdgcn_s_barrier();
      __builtin_amdgcn_sched_barrier(0);
      QUAD(1, 1);
      if (st) asm volatile("s_waitcnt vmcnt(2)" ::: "memory");
      else    asm volatile("s_waitcnt vmcnt(0)" ::: "memory");
      __builtin_amdgcn_s_barrier();
    }
    // ---- phase 4: buf1 quad(0,0) ----
#pragma unroll
    for (int mi = 0; mi < 4; mi++) { af[mi][0] = LDA(1, mi, 0); af[mi][1] = LDA(1, mi, 1); }
#pragma unroll
    for (int ni = 0; ni < 2; ni++) { bf[ni][0] = LDB(1, ni, 0); bf[ni][1] = LDB(1, ni, 1); }
    STAGE(g++);
    __builtin_amdgcn_s_barrier();
    asm volatile("s_waitcnt lgkmcnt(0)" ::: "memory");
    __builtin_amdgcn_sched_barrier(0);
    QUAD(0, 0);
    __builtin_amdgcn_s_barrier();
    // ---- phase 5: buf1 quad(0,1) ----
#pragma unroll
    for (int ni = 0; ni < 2; ni++) { bf[2 + ni][0] = LDB(1, 2 + ni, 0); bf[2 + ni][1] = LDB(1, 2 + ni, 1); }
    STAGE(g++);
    __builtin_amdgcn_s_barrier();
    asm volatile("s_waitcnt lgkmcnt(0)" ::: "memory");
    __builtin_amdgcn_sched_barrier(0);
    QUAD(0, 1);
    __builtin_amdgcn_s_barrier();
    // ---- phase 6: buf1 quad(1,0) ----
#pragma unroll
    for (int mi = 0; mi < 4; mi++) { af[mi][0] = LDA(1, 4 + mi, 0); af[mi][1] = LDA(1, 4 + mi, 1); }
    STAGE(g++);
    __builtin_amdgcn_s_barrier();
    asm volatile("s_waitcnt lgkmcnt(0)" ::: "memory");
    __builtin_amdgcn_sched_barrier(0);
    QUAD(1, 0);
    __builtin_amdgcn_s_barrier();
    // ---- phase 7: buf1 quad(1,1); gate buf0 before next iter ph0 ----
    {
      const bool st = (g < GMAX);
      STAGE(g++);
      __builtin_amdgcn_s_barrier();
      __builtin_amdgcn_sched_barrier(0);
      QUAD(1, 1);
      if (it + 1 < NIT) {
        if (st) asm volatile("s_waitcnt vmcnt(2)" ::: "memory");
        else    asm volatile("s_waitcnt vmcnt(0)" ::: "memory");
      }
      __builtin_amdgcn_s_barrier();
    }
  }

  // ---- epilogue ----
#pragma unroll
  for (int m = 0; m < 8; m++)
#pragma unroll
    for (int n = 0; n < 4; n++)
#pragma unroll
      for (int r = 0; r < 4; r++) {
        const size_t row = arow0 + (wr << 7) + (m << 4) + (lhi << 2) + r;
        const size_t col = brow0 + (wc << 6) + (n << 4) + llo;
        const float v = acc[m][n][r];
        if constexpr (sizeof(OT) == 2) C[row * N + col] = f2bf(v);
        else                           C[row * N + col] = v;
      }
}

// ---------------- GEMM: C[M][N] = A[M][K] * B[N][K]^T (m97 structure) ----------------
template <typename OT>
__global__ __launch_bounds__(256) void gemm_bt(const short* __restrict__ A,
                                               const short* __restrict__ B,
                                               OT* __restrict__ C,
                                               int M, int N, int K) {
  __shared__ __align__(16) short As[128 * 32];
  __shared__ __align__(16) short Bs[128 * 32];
  const int tid = threadIdx.x;
  const int wave = tid >> 6, lane = tid & 63;
  const int lhi = lane >> 4, llo = lane & 15;
  const int wm = wave >> 1, wn = wave & 1;
  const size_t arow0 = (size_t)blockIdx.x * 128;
  const size_t brow0 = (size_t)blockIdx.y * 128;
  const int srow = lane >> 2, schunk = lane & 3;

  f32x4 acc[4][4] = {};

  const short* aB = A + arow0 * K;
  const short* bB = B + brow0 * K;

  for (int k0 = 0; k0 < K; k0 += 32) {
    __syncthreads();
#pragma unroll
    for (int c = 0; c < 2; c++) {
      const int call = wave + c * 4;
      const int row = call * 16 + srow;
      __builtin_amdgcn_global_load_lds(
          (const __attribute__((address_space(1))) uint32_t*)(aB + (size_t)row * K + k0 + schunk * 8),
          (__attribute__((address_space(3))) uint32_t*)(As + call * 512), 16, 0, 0);
      __builtin_amdgcn_global_load_lds(
          (const __attribute__((address_space(1))) uint32_t*)(bB + (size_t)row * K + k0 + schunk * 8),
          (__attribute__((address_space(3))) uint32_t*)(Bs + call * 512), 16, 0, 0);
    }
    __syncthreads();

    short8 af[4], bf[4];
#pragma unroll
    for (int i = 0; i < 4; i++) {
      af[i] = *(const short8*)(As + (wm * 64 + i * 16 + llo) * 32 + lhi * 8);
      bf[i] = *(const short8*)(Bs + (wn * 64 + i * 16 + llo) * 32 + lhi * 8);
    }
#pragma unroll
    for (int i = 0; i < 4; i++)
#pragma unroll
      for (int j = 0; j < 4; j++)
        acc[i][j] = __builtin_amdgcn_mfma_f32_16x16x32_bf16(af[i], bf[j], acc[i][j], 0, 0, 0);
  }

#pragma unroll
  for (int i = 0; i < 4; i++)
#pragma unroll
    for (int j = 0; j < 4; j++)
#pragma unroll
      for (int r = 0; r < 4; r++) {
        size_t row = arow0 + wm * 64 + i * 16 + lhi * 4 + r;
        size_t col = brow0 + wn * 64 + j * 16 + llo;
        float v = acc[i][j][r];
        if constexpr (sizeof(OT) == 2) C[row * N + col] = f2bf(v);
        else                           C[row * N + col] = v;
      }
}

// ---------------- flash attention, causal GQA ----------------
__global__ __launch_bounds__(256, 3) void attn_fwd(const short* __restrict__ qkv,
                                                   short* __restrict__ aout) {
  const int qt = gridDim.y - 1 - blockIdx.y;
  const int h = blockIdx.x;
  const int kvh = h >> 2, g = h & 3;
  const int tid = threadIdx.x;
  const int wave = tid >> 6, lane = tid & 63;
  const int lhi = lane >> 4, llo = lane & 15;

  __shared__ __align__(16) short Ksm[64 * 128];
  __shared__ __align__(16) short Vsm[64 * 128];
  __shared__ __align__(16) short Psm[4][16 * 72];

  const float scale = 0.08838834764831845f;

  const int qrow = qt * 64 + wave * 16 + llo;
  const short* qbase = qkv + (size_t)qrow * QKV_LD + (kvh * 6 + g) * HD;
  short8 qf[4];
#pragma unroll
  for (int kk = 0; kk < 4; kk++) qf[kk] = *(const short8*)(qbase + kk * 32 + lhi * 8);

  f32x4 o[8] = {};
  float mrow[4], lrow[4];
#pragma unroll
  for (int r = 0; r < 4; r++) { mrow[r] = -1e30f; lrow[r] = 0.f; }

  const short* Kg = qkv + (kvh * 6 + 4) * HD;
  const short* Vg = qkv + (kvh * 6 + 5) * HD;

  const uint32_t vlane = (uint32_t)(uintptr_t)(__attribute__((address_space(3))) short*)Vsm
                         + (uint32_t)(lhi * 2048 + llo * 8);

  const int ntiles = qt + 1;
  for (int t = 0; t < ntiles; t++) {
    __syncthreads();
#pragma unroll
    for (int c = 0; c < 4; c++) {
      const int call = wave * 4 + c;
      const int row = call * 4 + lhi;
      const int sc = llo ^ (row & 7);
      __builtin_amdgcn_global_load_lds(
          (const __attribute__((address_space(1))) uint32_t*)(Kg + (size_t)(t * 64 + row) * QKV_LD + sc * 8),
          (__attribute__((address_space(3))) uint32_t*)(Ksm + call * 512), 16, 0, 0);
    }
#pragma unroll
    for (int c = 0; c < 4; c++) {
      const int idx = c * 256 + tid;
      const int vr = idx >> 4, vc = idx & 15;
      short8 v = *(const short8*)(Vg + (size_t)(t * 64 + vr) * QKV_LD + vc * 8);
      *(short8*)(Vsm + ((vr >> 2) * 8 + (vc >> 1)) * 64 + (vr & 3) * 16 + (vc & 1) * 8) = v;
    }
    __syncthreads();

    f32x4 s[4] = {};
#pragma unroll
    for (int n = 0; n < 4; n++) {
#pragma unroll
      for (int kk = 0; kk < 4; kk++) {
        const int krow = n * 16 + llo;
        const int ch = (kk * 4 + lhi) ^ (krow & 7);
        short8 kf = *(const short8*)(Ksm + krow * 128 + ch * 8);
        s[n] = __builtin_amdgcn_mfma_f32_16x16x32_bf16(qf[kk], kf, s[n], 0, 0, 0);
      }
    }

    float sv[4][4];
    const bool diag = (t == qt);
#pragma unroll
    for (int n = 0; n < 4; n++)
#pragma unroll
      for (int r = 0; r < 4; r++) {
        float x = s[n][r] * scale;
        if (diag && (n * 16 + llo > wave * 16 + lhi * 4 + r)) x = -1e30f;
        sv[n][r] = x;
      }

    float alpha[4];
#pragma unroll
    for (int r = 0; r < 4; r++) {
      float rm = fmaxf(fmaxf(sv[0][r], sv[1][r]), fmaxf(sv[2][r], sv[3][r]));
#pragma unroll
      for (int msk = 1; msk < 16; msk <<= 1) rm = fmaxf(rm, __shfl_xor(rm, msk));
      const float mnew = fmaxf(mrow[r], rm);
      alpha[r] = __expf(mrow[r] - mnew);
      mrow[r] = mnew;
      float rs = 0.f;
#pragma unroll
      for (int n = 0; n < 4; n++) {
        float p = __expf(sv[n][r] - mnew);
        sv[n][r] = p;
        rs += p;
      }
#pragma unroll
      for (int msk = 1; msk < 16; msk <<= 1) rs += __shfl_xor(rs, msk);
      lrow[r] = lrow[r] * alpha[r] + rs;
    }
#pragma unroll
    for (int nn = 0; nn < 8; nn++)
#pragma unroll
      for (int r = 0; r < 4; r++) o[nn][r] *= alpha[r];

    short* P = &Psm[wave][0];
#pragma unroll
    for (int n = 0; n < 4; n++)
#pragma unroll
      for (int r = 0; r < 4; r++)
        P[(lhi * 4 + r) * 72 + n * 16 + llo] = f2bf(sv[n][r]);

    short8 pa0 = *(const short8*)(P + llo * 72 + lhi * 8);
    short8 pa1 = *(const short8*)(P + llo * 72 + 32 + lhi * 8);
#pragma unroll
    for (int ks = 0; ks < 2; ks++) {
      uint2v vr_[8][2];
#pragma unroll
      for (int nn = 0; nn < 8; nn++)
#pragma unroll
        for (int hh = 0; hh < 2; hh++) {
          uint32_t a = vlane + (uint32_t)(ks * 8192 + hh * 1024 + nn * 128);
          asm volatile("ds_read_b64_tr_b16 %0, %1" : "=v"(vr_[nn][hh]) : "v"(a));
        }
      asm volatile("s_waitcnt lgkmcnt(0)" ::: "memory");
      __builtin_amdgcn_sched_barrier(0);
      const short8 pa = ks ? pa1 : pa0;
#pragma unroll
      for (int nn = 0; nn < 8; nn++) {
        int4v tv;
        tv[0] = (int)vr_[nn][0][0]; tv[1] = (int)vr_[nn][0][1];
        tv[2] = (int)vr_[nn][1][0]; tv[3] = (int)vr_[nn][1][1];
        o[nn] = __builtin_amdgcn_mfma_f32_16x16x32_bf16(pa, __builtin_bit_cast(short8, tv), o[nn], 0, 0, 0);
      }
    }
  }

#pragma unroll
  for (int nn = 0; nn < 8; nn++)
#pragma unroll
    for (int r = 0; r < 4; r++) {
      const size_t row = qt * 64 + wave * 16 + lhi * 4 + r;
      const size_t col = (size_t)h * HD + nn * 16 + llo;
      aout[row * OUT_LD + col] = f2bf(o[nn][r] / lrow[r]);
    }
}

// ---------------- launch ----------------
extern "C" void kernel_launch(void* const* d_in, const int* in_sizes, int n_in,
                              void* d_out, int out_size, void* d_ws, size_t ws_size,
                              hipStream_t stream) {
  const float* tokens = (const float*)d_in[0];
  const float* wqkv   = (const float*)d_in[1];
  const float* wproj  = (const float*)d_in[2];
  float* out = (float*)d_out;

  short* tok_bf   = (short*)d_ws;
  short* wqkv_bf  = tok_bf   + (size_t)SEQ * HIDDEN;
  short* wproj_bf = wqkv_bf  + (size_t)QKV_LD * HIDDEN;
  short* qkv_bf   = wproj_bf + (size_t)HIDDEN * OUT_LD;
  short* attn_bf  = qkv_bf   + (size_t)SEQ * QKV_LD;

  cast_kernel<<<2048, 256, 0, stream>>>(tokens, tok_bf, SEQ * HIDDEN / 4);
  cast_kernel<<<2048, 256, 0, stream>>>(wqkv, wqkv_bf, QKV_LD * HIDDEN / 4);
  cast_kernel<<<2048, 256, 0, stream>>>(wproj, wproj_bf, HIDDEN * OUT_LD / 4);

  // QKV: M=2048, N=6144 -> 8 x 24 = 192 workgroups of 256x256
  gemm256<short><<<192, 512, 0, stream>>>(tok_bf, wqkv_bf, qkv_bf, SEQ, QKV_LD, HIDDEN, QKV_LD / 256);

  attn_fwd<<<dim3(NHEADS, SEQ / 64), 256, 0, stream>>>(qkv_bf, attn_bf);

  gemm_bt<float><<<dim3(SEQ / 128, OUT_LD / 128), 256, 0, stream>>>(
      attn_bf, wproj_bf, out, SEQ, OUT_LD, HIDDEN);
}

// Round 5
// 391.279 us; speedup vs baseline: 1.3938x; 1.0237x over previous
//
#include <hip/hip_runtime.h>
#include <hip/hip_bf16.h>
#include <stdint.h>

#define SEQ 2048
#define HIDDEN 4096
#define NHEADS 32
#define HD 128
#define QKV_LD 6144
#define OUT_LD 4096

typedef __attribute__((ext_vector_type(8))) short short8;
typedef __attribute__((ext_vector_type(4))) short short4v;
typedef __attribute__((ext_vector_type(4))) float f32x4;
typedef __attribute__((ext_vector_type(4))) int int4v;
typedef __attribute__((ext_vector_type(2))) unsigned int uint2v;
typedef __attribute__((ext_vector_type(4))) float float4v;

__device__ __forceinline__ short f2bf(float f) {
  uint32_t u = __builtin_bit_cast(uint32_t, f);
  u += 0x7fff + ((u >> 16) & 1);   // RNE
  return (short)(u >> 16);
}

// ---------------- cast fp32 -> bf16 ----------------
__global__ void cast_kernel(const float* __restrict__ in, short* __restrict__ out, int n4) {
  int stride = gridDim.x * blockDim.x;
  for (int i = blockIdx.x * blockDim.x + threadIdx.x; i < n4; i += stride) {
    float4v v = ((const float4v*)in)[i];
    short4v o;
    o[0] = f2bf(v[0]); o[1] = f2bf(v[1]); o[2] = f2bf(v[2]); o[3] = f2bf(v[3]);
    ((short4v*)out)[i] = o;
  }
}

// ============ 256x256 8-phase GEMM: C[M][N] = A[M][K] * B[N][K]^T ============
// 512 thr = 8 waves (2M x 4N), BK=64, double-buffered 128KB LDS,
// counted-vmcnt pipeline (each tile's 4 quarters staged in 2 adjacent phases,
// gated 3+ phases later), chunk^=row&7 LDS swizzle, setprio MFMA clusters.
template <typename OT>
__global__ __launch_bounds__(512, 2) void gemm256(const short* __restrict__ A,
                                                  const short* __restrict__ B,
                                                  OT* __restrict__ C,
                                                  int M, int N, int K, int NT) {
  __shared__ __align__(16) short lds[65536];  // A: [0,32K) shorts, B: [32K,64K); per side 2 bufs x 16384
  const int tid = threadIdx.x;
  const int w = tid >> 6, lane = tid & 63;
  const int wr = w >> 2, wc = w & 3;
  const int llo = lane & 15, lhi = lane >> 4;

  // T1 bijective XCD swizzle (nwg % 8 == 0)
  const int nwg = gridDim.x;
  const int cpx = nwg >> 3;
  const int work = ((int)blockIdx.x & 7) * cpx + ((int)blockIdx.x >> 3);
  const int mt = work / NT, nt = work % NT;
  const size_t arow0 = (size_t)mt * 256, brow0 = (size_t)nt * 256;
  const short* Ab = A + arow0 * K;
  const short* Bb = B + brow0 * K;

  const int s_r = lane >> 3;   // staging: row within 8-row slice
  const int s_c = lane & 7;    // staging: 16B chunk (of 8 per 128B row)

  const int NKT = K >> 6;      // K-tiles of 64
  const int NIT = NKT >> 1;

  f32x4 acc[8][4] = {};
  short8 af[4][2], bf[4][2];

  // stage quarter h of K-tile kt (h: 0=A lo,1=A hi,2=B lo,3=B hi); 2 loads/thread
  auto STAGE = [&](int kt, int h) {
    const int bufd = kt & 1;
    const int side = h >> 1;
    const int htrow = (h & 1) << 7;
    const short* gb = side ? Bb : Ab;
#pragma unroll
    for (int c = 0; c < 2; c++) {
      const int slice = (c << 3) + w;              // 0..15
      const int rowrel = htrow + (slice << 3) + s_r;
      const short* src = gb + (size_t)rowrel * K + (kt << 6) + ((s_c ^ (rowrel & 7)) << 3);
      short* dst = lds + (side << 15) + (bufd << 14) + htrow * 64 + (slice << 9);
      __builtin_amdgcn_global_load_lds(
          (const __attribute__((address_space(1))) uint32_t*)src,
          (__attribute__((address_space(3))) uint32_t*)dst, 16, 0, 0);
    }
  };

  auto LDA = [&](int bufd, int m, int kk) -> short8 {
    const int row = (wr << 7) + (m << 4) + llo;
    const int ch = ((kk << 2) + lhi) ^ (row & 7);
    return *(const short8*)(lds + (bufd << 14) + row * 64 + (ch << 3));
  };
  auto LDB = [&](int bufd, int n, int kk) -> short8 {
    const int row = (wc << 6) + (n << 4) + llo;
    const int ch = ((kk << 2) + lhi) ^ (row & 7);
    return *(const short8*)(lds + 32768 + (bufd << 14) + row * 64 + (ch << 3));
  };
  auto QUAD = [&](int mh, int nh) {
    __builtin_amdgcn_s_setprio(1);
#pragma unroll
    for (int mi = 0; mi < 4; mi++)
#pragma unroll
      for (int ni = 0; ni < 2; ni++)
#pragma unroll
        for (int kk = 0; kk < 2; kk++)
          acc[(mh << 2) + mi][(nh << 1) + ni] = __builtin_amdgcn_mfma_f32_16x16x32_bf16(
              af[mi][kk], bf[(nh << 1) + ni][kk], acc[(mh << 2) + mi][(nh << 1) + ni], 0, 0, 0);
    __builtin_amdgcn_s_setprio(0);
  };

  // ---- prologue: tile0 all quarters + tile1 quarters 0,1; gate tile0 ----
  STAGE(0, 0); STAGE(0, 1); STAGE(0, 2); STAGE(0, 3);
  STAGE(1, 0); STAGE(1, 1);
  asm volatile("s_waitcnt vmcnt(4)" ::: "memory");
  __builtin_amdgcn_s_barrier();

  for (int it = 0; it < NIT; ++it) {
    const int T1 = 2 * it + 1;
    const bool stN = (it + 1 < NIT);  // tiles T1+1, T1+2 exist
    // ---- phase 0: buf0 quad(0,0); reads af[m0-3], bf[n0-1]; stage buf1 tile q2,q3 ----
#pragma unroll
    for (int mi = 0; mi < 4; mi++) { af[mi][0] = LDA(0, mi, 0); af[mi][1] = LDA(0, mi, 1); }
#pragma unroll
    for (int ni = 0; ni < 2; ni++) { bf[ni][0] = LDB(0, ni, 0); bf[ni][1] = LDB(0, ni, 1); }
    STAGE(T1, 2); STAGE(T1, 3);
    __builtin_amdgcn_s_barrier();
    asm volatile("s_waitcnt lgkmcnt(0)" ::: "memory");
    __builtin_amdgcn_sched_barrier(0);
    QUAD(0, 0);
    __builtin_amdgcn_s_barrier();
    // ---- phase 1: buf0 quad(0,1); reads bf[n2-3] ----
#pragma unroll
    for (int ni = 0; ni < 2; ni++) { bf[2 + ni][0] = LDB(0, 2 + ni, 0); bf[2 + ni][1] = LDB(0, 2 + ni, 1); }
    __builtin_amdgcn_s_barrier();
    asm volatile("s_waitcnt lgkmcnt(0)" ::: "memory");
    __builtin_amdgcn_sched_barrier(0);
    QUAD(0, 1);
    __builtin_amdgcn_s_barrier();
    // ---- phase 2: buf0 quad(1,0); reads af[m4-7] (buf0 fully reg-consumed after this) ----
#pragma unroll
    for (int mi = 0; mi < 4; mi++) { af[mi][0] = LDA(0, 4 + mi, 0); af[mi][1] = LDA(0, 4 + mi, 1); }
    __builtin_amdgcn_s_barrier();
    asm volatile("s_waitcnt lgkmcnt(0)" ::: "memory");
    __builtin_amdgcn_sched_barrier(0);
    QUAD(1, 0);
    __builtin_amdgcn_s_barrier();
    // ---- phase 3: buf0 quad(1,1); buf0 writable -> stage next-buf0-tile q0,q1; gate buf1 ----
    if (stN) { STAGE(T1 + 1, 0); STAGE(T1 + 1, 1); }
    __builtin_amdgcn_s_barrier();
    __builtin_amdgcn_sched_barrier(0);
    QUAD(1, 1);
    if (stN) asm volatile("s_waitcnt vmcnt(4)" ::: "memory");
    else     asm volatile("s_waitcnt vmcnt(0)" ::: "memory");
    __builtin_amdgcn_s_barrier();
    // ---- phase 4: buf1 quad(0,0); stage next-buf0-tile q2,q3 ----
#pragma unroll
    for (int mi = 0; mi < 4; mi++) { af[mi][0] = LDA(1, mi, 0); af[mi][1] = LDA(1, mi, 1); }
#pragma unroll
    for (int ni = 0; ni < 2; ni++) { bf[ni][0] = LDB(1, ni, 0); bf[ni][1] = LDB(1, ni, 1); }
    if (stN) { STAGE(T1 + 1, 2); STAGE(T1 + 1, 3); }
    __builtin_amdgcn_s_barrier();
    asm volatile("s_waitcnt lgkmcnt(0)" ::: "memory");
    __builtin_amdgcn_sched_barrier(0);
    QUAD(0, 0);
    __builtin_amdgcn_s_barrier();
    // ---- phase 5: buf1 quad(0,1) ----
#pragma unroll
    for (int ni = 0; ni < 2; ni++) { bf[2 + ni][0] = LDB(1, 2 + ni, 0); bf[2 + ni][1] = LDB(1, 2 + ni, 1); }
    __builtin_amdgcn_s_barrier();
    asm volatile("s_waitcnt lgkmcnt(0)" ::: "memory");
    __builtin_amdgcn_sched_barrier(0);
    QUAD(0, 1);
    __builtin_amdgcn_s_barrier();
    // ---- phase 6: buf1 quad(1,0) ----
#pragma unroll
    for (int mi = 0; mi < 4; mi++) { af[mi][0] = LDA(1, 4 + mi, 0); af[mi][1] = LDA(1, 4 + mi, 1); }
    __builtin_amdgcn_s_barrier();
    asm volatile("s_waitcnt lgkmcnt(0)" ::: "memory");
    __builtin_amdgcn_sched_barrier(0);
    QUAD(1, 0);
    __builtin_amdgcn_s_barrier();
    // ---- phase 7: buf1 quad(1,1); buf1 writable -> stage next-buf1-tile q0,q1; gate buf0 ----
    if (stN) { STAGE(T1 + 2, 0); STAGE(T1 + 2, 1); }
    __builtin_amdgcn_s_barrier();
    __builtin_amdgcn_sched_barrier(0);
    QUAD(1, 1);
    if (stN) asm volatile("s_waitcnt vmcnt(4)" ::: "memory");
    __builtin_amdgcn_s_barrier();
  }

  // ---- epilogue ----
#pragma unroll
  for (int m = 0; m < 8; m++)
#pragma unroll
    for (int n = 0; n < 4; n++)
#pragma unroll
      for (int r = 0; r < 4; r++) {
        const size_t row = arow0 + (wr << 7) + (m << 4) + (lhi << 2) + r;
        const size_t col = brow0 + (wc << 6) + (n << 4) + llo;
        const float v = acc[m][n][r];
        if constexpr (sizeof(OT) == 2) C[row * N + col] = f2bf(v);
        else                           C[row * N + col] = v;
      }
}

// ---------------- GEMM: C[M][N] = A[M][K] * B[N][K]^T (m97 structure) ----------------
template <typename OT>
__global__ __launch_bounds__(256) void gemm_bt(const short* __restrict__ A,
                                               const short* __restrict__ B,
                                               OT* __restrict__ C,
                                               int M, int N, int K) {
  __shared__ __align__(16) short As[128 * 32];
  __shared__ __align__(16) short Bs[128 * 32];
  const int tid = threadIdx.x;
  const int wave = tid >> 6, lane = tid & 63;
  const int lhi = lane >> 4, llo = lane & 15;
  const int wm = wave >> 1, wn = wave & 1;
  const size_t arow0 = (size_t)blockIdx.x * 128;
  const size_t brow0 = (size_t)blockIdx.y * 128;
  const int srow = lane >> 2, schunk = lane & 3;

  f32x4 acc[4][4] = {};

  const short* aB = A + arow0 * K;
  const short* bB = B + brow0 * K;

  for (int k0 = 0; k0 < K; k0 += 32) {
    __syncthreads();
#pragma unroll
    for (int c = 0; c < 2; c++) {
      const int call = wave + c * 4;
      const int row = call * 16 + srow;
      __builtin_amdgcn_global_load_lds(
          (const __attribute__((address_space(1))) uint32_t*)(aB + (size_t)row * K + k0 + schunk * 8),
          (__attribute__((address_space(3))) uint32_t*)(As + call * 512), 16, 0, 0);
      __builtin_amdgcn_global_load_lds(
          (const __attribute__((address_space(1))) uint32_t*)(bB + (size_t)row * K + k0 + schunk * 8),
          (__attribute__((address_space(3))) uint32_t*)(Bs + call * 512), 16, 0, 0);
    }
    __syncthreads();

    short8 af[4], bf[4];
#pragma unroll
    for (int i = 0; i < 4; i++) {
      af[i] = *(const short8*)(As + (wm * 64 + i * 16 + llo) * 32 + lhi * 8);
      bf[i] = *(const short8*)(Bs + (wn * 64 + i * 16 + llo) * 32 + lhi * 8);
    }
#pragma unroll
    for (int i = 0; i < 4; i++)
#pragma unroll
      for (int j = 0; j < 4; j++)
        acc[i][j] = __builtin_amdgcn_mfma_f32_16x16x32_bf16(af[i], bf[j], acc[i][j], 0, 0, 0);
  }

#pragma unroll
  for (int i = 0; i < 4; i++)
#pragma unroll
    for (int j = 0; j < 4; j++)
#pragma unroll
      for (int r = 0; r < 4; r++) {
        size_t row = arow0 + wm * 64 + i * 16 + lhi * 4 + r;
        size_t col = brow0 + wn * 64 + j * 16 + llo;
        float v = acc[i][j][r];
        if constexpr (sizeof(OT) == 2) C[row * N + col] = f2bf(v);
        else                           C[row * N + col] = v;
      }
}

// ---------------- flash attention, causal GQA ----------------
__global__ __launch_bounds__(256, 3) void attn_fwd(const short* __restrict__ qkv,
                                                   short* __restrict__ aout) {
  const int qt = gridDim.y - 1 - blockIdx.y;
  const int h = blockIdx.x;
  const int kvh = h >> 2, g = h & 3;
  const int tid = threadIdx.x;
  const int wave = tid >> 6, lane = tid & 63;
  const int lhi = lane >> 4, llo = lane & 15;

  __shared__ __align__(16) short Ksm[64 * 128];
  __shared__ __align__(16) short Vsm[64 * 128];
  __shared__ __align__(16) short Psm[4][16 * 72];

  const float scale = 0.08838834764831845f;

  const int qrow = qt * 64 + wave * 16 + llo;
  const short* qbase = qkv + (size_t)qrow * QKV_LD + (kvh * 6 + g) * HD;
  short8 qf[4];
#pragma unroll
  for (int kk = 0; kk < 4; kk++) qf[kk] = *(const short8*)(qbase + kk * 32 + lhi * 8);

  f32x4 o[8] = {};
  float mrow[4], lrow[4];
#pragma unroll
  for (int r = 0; r < 4; r++) { mrow[r] = -1e30f; lrow[r] = 0.f; }

  const short* Kg = qkv + (kvh * 6 + 4) * HD;
  const short* Vg = qkv + (kvh * 6 + 5) * HD;

  const uint32_t vlane = (uint32_t)(uintptr_t)(__attribute__((address_space(3))) short*)Vsm
                         + (uint32_t)(lhi * 2048 + llo * 8);

  const int ntiles = qt + 1;
  for (int t = 0; t < ntiles; t++) {
    __syncthreads();
#pragma unroll
    for (int c = 0; c < 4; c++) {
      const int call = wave * 4 + c;
      const int row = call * 4 + lhi;
      const int sc = llo ^ (row & 7);
      __builtin_amdgcn_global_load_lds(
          (const __attribute__((address_space(1))) uint32_t*)(Kg + (size_t)(t * 64 + row) * QKV_LD + sc * 8),
          (__attribute__((address_space(3))) uint32_t*)(Ksm + call * 512), 16, 0, 0);
    }
#pragma unroll
    for (int c = 0; c < 4; c++) {
      const int idx = c * 256 + tid;
      const int vr = idx >> 4, vc = idx & 15;
      short8 v = *(const short8*)(Vg + (size_t)(t * 64 + vr) * QKV_LD + vc * 8);
      *(short8*)(Vsm + ((vr >> 2) * 8 + (vc >> 1)) * 64 + (vr & 3) * 16 + (vc & 1) * 8) = v;
    }
    __syncthreads();

    f32x4 s[4] = {};
#pragma unroll
    for (int n = 0; n < 4; n++) {
#pragma unroll
      for (int kk = 0; kk < 4; kk++) {
        const int krow = n * 16 + llo;
        const int ch = (kk * 4 + lhi) ^ (krow & 7);
        short8 kf = *(const short8*)(Ksm + krow * 128 + ch * 8);
        s[n] = __builtin_amdgcn_mfma_f32_16x16x32_bf16(qf[kk], kf, s[n], 0, 0, 0);
      }
    }

    float sv[4][4];
    const bool diag = (t == qt);
#pragma unroll
    for (int n = 0; n < 4; n++)
#pragma unroll
      for (int r = 0; r < 4; r++) {
        float x = s[n][r] * scale;
        if (diag && (n * 16 + llo > wave * 16 + lhi * 4 + r)) x = -1e30f;
        sv[n][r] = x;
      }

    float alpha[4];
#pragma unroll
    for (int r = 0; r < 4; r++) {
      float rm = fmaxf(fmaxf(sv[0][r], sv[1][r]), fmaxf(sv[2][r], sv[3][r]));
#pragma unroll
      for (int msk = 1; msk < 16; msk <<= 1) rm = fmaxf(rm, __shfl_xor(rm, msk));
      const float mnew = fmaxf(mrow[r], rm);
      alpha[r] = __expf(mrow[r] - mnew);
      mrow[r] = mnew;
      float rs = 0.f;
#pragma unroll
      for (int n = 0; n < 4; n++) {
        float p = __expf(sv[n][r] - mnew);
        sv[n][r] = p;
        rs += p;
      }
#pragma unroll
      for (int msk = 1; msk < 16; msk <<= 1) rs += __shfl_xor(rs, msk);
      lrow[r] = lrow[r] * alpha[r] + rs;
    }
#pragma unroll
    for (int nn = 0; nn < 8; nn++)
#pragma unroll
      for (int r = 0; r < 4; r++) o[nn][r] *= alpha[r];

    short* P = &Psm[wave][0];
#pragma unroll
    for (int n = 0; n < 4; n++)
#pragma unroll
      for (int r = 0; r < 4; r++)
        P[(lhi * 4 + r) * 72 + n * 16 + llo] = f2bf(sv[n][r]);

    short8 pa0 = *(const short8*)(P + llo * 72 + lhi * 8);
    short8 pa1 = *(const short8*)(P + llo * 72 + 32 + lhi * 8);
#pragma unroll
    for (int ks = 0; ks < 2; ks++) {
      uint2v vr_[8][2];
#pragma unroll
      for (int nn = 0; nn < 8; nn++)
#pragma unroll
        for (int hh = 0; hh < 2; hh++) {
          uint32_t a = vlane + (uint32_t)(ks * 8192 + hh * 1024 + nn * 128);
          asm volatile("ds_read_b64_tr_b16 %0, %1" : "=v"(vr_[nn][hh]) : "v"(a));
        }
      asm volatile("s_waitcnt lgkmcnt(0)" ::: "memory");
      __builtin_amdgcn_sched_barrier(0);
      const short8 pa = ks ? pa1 : pa0;
#pragma unroll
      for (int nn = 0; nn < 8; nn++) {
        int4v tv;
        tv[0] = (int)vr_[nn][0][0]; tv[1] = (int)vr_[nn][0][1];
        tv[2] = (int)vr_[nn][1][0]; tv[3] = (int)vr_[nn][1][1];
        o[nn] = __builtin_amdgcn_mfma_f32_16x16x32_bf16(pa, __builtin_bit_cast(short8, tv), o[nn], 0, 0, 0);
      }
    }
  }

#pragma unroll
  for (int nn = 0; nn < 8; nn++)
#pragma unroll
    for (int r = 0; r < 4; r++) {
      const size_t row = qt * 64 + wave * 16 + lhi * 4 + r;
      const size_t col = (size_t)h * HD + nn * 16 + llo;
      aout[row * OUT_LD + col] = f2bf(o[nn][r] / lrow[r]);
    }
}

// ---------------- launch ----------------
extern "C" void kernel_launch(void* const* d_in, const int* in_sizes, int n_in,
                              void* d_out, int out_size, void* d_ws, size_t ws_size,
                              hipStream_t stream) {
  const float* tokens = (const float*)d_in[0];
  const float* wqkv   = (const float*)d_in[1];
  const float* wproj  = (const float*)d_in[2];
  float* out = (float*)d_out;

  short* tok_bf   = (short*)d_ws;
  short* wqkv_bf  = tok_bf   + (size_t)SEQ * HIDDEN;
  short* wproj_bf = wqkv_bf  + (size_t)QKV_LD * HIDDEN;
  short* qkv_bf   = wproj_bf + (size_t)HIDDEN * OUT_LD;
  short* attn_bf  = qkv_bf   + (size_t)SEQ * QKV_LD;

  cast_kernel<<<2048, 256, 0, stream>>>(tokens, tok_bf, SEQ * HIDDEN / 4);
  cast_kernel<<<2048, 256, 0, stream>>>(wqkv, wqkv_bf, QKV_LD * HIDDEN / 4);
  cast_kernel<<<2048, 256, 0, stream>>>(wproj, wproj_bf, HIDDEN * OUT_LD / 4);

  // QKV: M=2048, N=6144 -> 8 x 24 = 192 workgroups of 256x256
  gemm256<short><<<192, 512, 0, stream>>>(tok_bf, wqkv_bf, qkv_bf, SEQ, QKV_LD, HIDDEN, QKV_LD / 256);

  attn_fwd<<<dim3(NHEADS, SEQ / 64), 256, 0, stream>>>(qkv_bf, attn_bf);

  gemm_bt<float><<<dim3(SEQ / 128, OUT_LD / 128), 256, 0, stream>>>(
      attn_bf, wproj_bf, out, SEQ, OUT_LD, HIDDEN);
}

// Round 6
// 373.947 us; speedup vs baseline: 1.4584x; 1.0463x over previous
//
#include <hip/hip_runtime.h>
#include <hip/hip_bf16.h>
#include <stdint.h>

#define SEQ 2048
#define HIDDEN 4096
#define NHEADS 32
#define HD 128
#define QKV_LD 6144
#define OUT_LD 4096

typedef __attribute__((ext_vector_type(8))) short short8;
typedef __attribute__((ext_vector_type(4))) short short4v;
typedef __attribute__((ext_vector_type(4))) float f32x4;
typedef __attribute__((ext_vector_type(4))) int int4v;
typedef __attribute__((ext_vector_type(2))) unsigned int uint2v;
typedef __attribute__((ext_vector_type(4))) float float4v;

__device__ __forceinline__ short f2bf(float f) {
  uint32_t u = __builtin_bit_cast(uint32_t, f);
  u += 0x7fff + ((u >> 16) & 1);   // RNE
  return (short)(u >> 16);
}

// ---------------- cast fp32 -> bf16 ----------------
__global__ void cast_kernel(const float* __restrict__ in, short* __restrict__ out, int n4) {
  int stride = gridDim.x * blockDim.x;
  for (int i = blockIdx.x * blockDim.x + threadIdx.x; i < n4; i += stride) {
    float4v v = ((const float4v*)in)[i];
    short4v o;
    o[0] = f2bf(v[0]); o[1] = f2bf(v[1]); o[2] = f2bf(v[2]); o[3] = f2bf(v[3]);
    ((short4v*)out)[i] = o;
  }
}

// ============ 256x256 8-phase GEMM: C[M][N] = A[M][K] * B[N][K]^T ============
template <typename OT>
__global__ __launch_bounds__(512, 2) void gemm256(const short* __restrict__ A,
                                                  const short* __restrict__ B,
                                                  OT* __restrict__ C,
                                                  int M, int N, int K, int NT) {
  __shared__ __align__(16) short lds[65536];
  const int tid = threadIdx.x;
  const int w = tid >> 6, lane = tid & 63;
  const int wr = w >> 2, wc = w & 3;
  const int llo = lane & 15, lhi = lane >> 4;

  const int nwg = gridDim.x;
  const int cpx = nwg >> 3;
  const int work = ((int)blockIdx.x & 7) * cpx + ((int)blockIdx.x >> 3);
  const int mt = work / NT, nt = work % NT;
  const size_t arow0 = (size_t)mt * 256, brow0 = (size_t)nt * 256;
  const short* Ab = A + arow0 * K;
  const short* Bb = B + brow0 * K;

  const int s_r = lane >> 3;
  const int s_c = lane & 7;

  const int NKT = K >> 6;
  const int NIT = NKT >> 1;

  f32x4 acc[8][4] = {};
  short8 af[4][2], bf[4][2];

  auto STAGE = [&](int kt, int h) {
    const int bufd = kt & 1;
    const int side = h >> 1;
    const int htrow = (h & 1) << 7;
    const short* gb = side ? Bb : Ab;
#pragma unroll
    for (int c = 0; c < 2; c++) {
      const int slice = (c << 3) + w;
      const int rowrel = htrow + (slice << 3) + s_r;
      const short* src = gb + (size_t)rowrel * K + (kt << 6) + ((s_c ^ (rowrel & 7)) << 3);
      short* dst = lds + (side << 15) + (bufd << 14) + htrow * 64 + (slice << 9);
      __builtin_amdgcn_global_load_lds(
          (const __attribute__((address_space(1))) uint32_t*)src,
          (__attribute__((address_space(3))) uint32_t*)dst, 16, 0, 0);
    }
  };

  auto LDA = [&](int bufd, int m, int kk) -> short8 {
    const int row = (wr << 7) + (m << 4) + llo;
    const int ch = ((kk << 2) + lhi) ^ (row & 7);
    return *(const short8*)(lds + (bufd << 14) + row * 64 + (ch << 3));
  };
  auto LDB = [&](int bufd, int n, int kk) -> short8 {
    const int row = (wc << 6) + (n << 4) + llo;
    const int ch = ((kk << 2) + lhi) ^ (row & 7);
    return *(const short8*)(lds + 32768 + (bufd << 14) + row * 64 + (ch << 3));
  };
  auto QUAD = [&](int mh, int nh) {
    __builtin_amdgcn_s_setprio(1);
#pragma unroll
    for (int mi = 0; mi < 4; mi++)
#pragma unroll
      for (int ni = 0; ni < 2; ni++)
#pragma unroll
        for (int kk = 0; kk < 2; kk++)
          acc[(mh << 2) + mi][(nh << 1) + ni] = __builtin_amdgcn_mfma_f32_16x16x32_bf16(
              af[mi][kk], bf[(nh << 1) + ni][kk], acc[(mh << 2) + mi][(nh << 1) + ni], 0, 0, 0);
    __builtin_amdgcn_s_setprio(0);
  };

  STAGE(0, 0); STAGE(0, 1); STAGE(0, 2); STAGE(0, 3);
  STAGE(1, 0); STAGE(1, 1);
  asm volatile("s_waitcnt vmcnt(4)" ::: "memory");
  __builtin_amdgcn_s_barrier();

  for (int it = 0; it < NIT; ++it) {
    const int T1 = 2 * it + 1;
    const bool stN = (it + 1 < NIT);
#pragma unroll
    for (int mi = 0; mi < 4; mi++) { af[mi][0] = LDA(0, mi, 0); af[mi][1] = LDA(0, mi, 1); }
#pragma unroll
    for (int ni = 0; ni < 2; ni++) { bf[ni][0] = LDB(0, ni, 0); bf[ni][1] = LDB(0, ni, 1); }
    STAGE(T1, 2); STAGE(T1, 3);
    __builtin_amdgcn_s_barrier();
    asm volatile("s_waitcnt lgkmcnt(0)" ::: "memory");
    __builtin_amdgcn_sched_barrier(0);
    QUAD(0, 0);
    __builtin_amdgcn_s_barrier();
#pragma unroll
    for (int ni = 0; ni < 2; ni++) { bf[2 + ni][0] = LDB(0, 2 + ni, 0); bf[2 + ni][1] = LDB(0, 2 + ni, 1); }
    __builtin_amdgcn_s_barrier();
    asm volatile("s_waitcnt lgkmcnt(0)" ::: "memory");
    __builtin_amdgcn_sched_barrier(0);
    QUAD(0, 1);
    __builtin_amdgcn_s_barrier();
#pragma unroll
    for (int mi = 0; mi < 4; mi++) { af[mi][0] = LDA(0, 4 + mi, 0); af[mi][1] = LDA(0, 4 + mi, 1); }
    __builtin_amdgcn_s_barrier();
    asm volatile("s_waitcnt lgkmcnt(0)" ::: "memory");
    __builtin_amdgcn_sched_barrier(0);
    QUAD(1, 0);
    __builtin_amdgcn_s_barrier();
    if (stN) { STAGE(T1 + 1, 0); STAGE(T1 + 1, 1); }
    __builtin_amdgcn_s_barrier();
    __builtin_amdgcn_sched_barrier(0);
    QUAD(1, 1);
    if (stN) asm volatile("s_waitcnt vmcnt(4)" ::: "memory");
    else     asm volatile("s_waitcnt vmcnt(0)" ::: "memory");
    __builtin_amdgcn_s_barrier();
#pragma unroll
    for (int mi = 0; mi < 4; mi++) { af[mi][0] = LDA(1, mi, 0); af[mi][1] = LDA(1, mi, 1); }
#pragma unroll
    for (int ni = 0; ni < 2; ni++) { bf[ni][0] = LDB(1, ni, 0); bf[ni][1] = LDB(1, ni, 1); }
    if (stN) { STAGE(T1 + 1, 2); STAGE(T1 + 1, 3); }
    __builtin_amdgcn_s_barrier();
    asm volatile("s_waitcnt lgkmcnt(0)" ::: "memory");
    __builtin_amdgcn_sched_barrier(0);
    QUAD(0, 0);
    __builtin_amdgcn_s_barrier();
#pragma unroll
    for (int ni = 0; ni < 2; ni++) { bf[2 + ni][0] = LDB(1, 2 + ni, 0); bf[2 + ni][1] = LDB(1, 2 + ni, 1); }
    __builtin_amdgcn_s_barrier();
    asm volatile("s_waitcnt lgkmcnt(0)" ::: "memory");
    __builtin_amdgcn_sched_barrier(0);
    QUAD(0, 1);
    __builtin_amdgcn_s_barrier();
#pragma unroll
    for (int mi = 0; mi < 4; mi++) { af[mi][0] = LDA(1, 4 + mi, 0); af[mi][1] = LDA(1, 4 + mi, 1); }
    __builtin_amdgcn_s_barrier();
    asm volatile("s_waitcnt lgkmcnt(0)" ::: "memory");
    __builtin_amdgcn_sched_barrier(0);
    QUAD(1, 0);
    __builtin_amdgcn_s_barrier();
    if (stN) { STAGE(T1 + 2, 0); STAGE(T1 + 2, 1); }
    __builtin_amdgcn_s_barrier();
    __builtin_amdgcn_sched_barrier(0);
    QUAD(1, 1);
    if (stN) asm volatile("s_waitcnt vmcnt(4)" ::: "memory");
    __builtin_amdgcn_s_barrier();
  }

#pragma unroll
  for (int m = 0; m < 8; m++)
#pragma unroll
    for (int n = 0; n < 4; n++)
#pragma unroll
      for (int r = 0; r < 4; r++) {
        const size_t row = arow0 + (wr << 7) + (m << 4) + (lhi << 2) + r;
        const size_t col = brow0 + (wc << 6) + (n << 4) + llo;
        const float v = acc[m][n][r];
        if constexpr (sizeof(OT) == 2) C[row * N + col] = f2bf(v);
        else                           C[row * N + col] = v;
      }
}

// ---------------- GEMM: C[M][N] = A[M][K] * B[N][K]^T (m97 structure) ----------------
template <typename OT>
__global__ __launch_bounds__(256) void gemm_bt(const short* __restrict__ A,
                                               const short* __restrict__ B,
                                               OT* __restrict__ C,
                                               int M, int N, int K) {
  __shared__ __align__(16) short As[128 * 32];
  __shared__ __align__(16) short Bs[128 * 32];
  const int tid = threadIdx.x;
  const int wave = tid >> 6, lane = tid & 63;
  const int lhi = lane >> 4, llo = lane & 15;
  const int wm = wave >> 1, wn = wave & 1;
  const size_t arow0 = (size_t)blockIdx.x * 128;
  const size_t brow0 = (size_t)blockIdx.y * 128;
  const int srow = lane >> 2, schunk = lane & 3;

  f32x4 acc[4][4] = {};

  const short* aB = A + arow0 * K;
  const short* bB = B + brow0 * K;

  for (int k0 = 0; k0 < K; k0 += 32) {
    __syncthreads();
#pragma unroll
    for (int c = 0; c < 2; c++) {
      const int call = wave + c * 4;
      const int row = call * 16 + srow;
      __builtin_amdgcn_global_load_lds(
          (const __attribute__((address_space(1))) uint32_t*)(aB + (size_t)row * K + k0 + schunk * 8),
          (__attribute__((address_space(3))) uint32_t*)(As + call * 512), 16, 0, 0);
      __builtin_amdgcn_global_load_lds(
          (const __attribute__((address_space(1))) uint32_t*)(bB + (size_t)row * K + k0 + schunk * 8),
          (__attribute__((address_space(3))) uint32_t*)(Bs + call * 512), 16, 0, 0);
    }
    __syncthreads();

    short8 af[4], bf[4];
#pragma unroll
    for (int i = 0; i < 4; i++) {
      af[i] = *(const short8*)(As + (wm * 64 + i * 16 + llo) * 32 + lhi * 8);
      bf[i] = *(const short8*)(Bs + (wn * 64 + i * 16 + llo) * 32 + lhi * 8);
    }
#pragma unroll
    for (int i = 0; i < 4; i++)
#pragma unroll
      for (int j = 0; j < 4; j++)
        acc[i][j] = __builtin_amdgcn_mfma_f32_16x16x32_bf16(af[i], bf[j], acc[i][j], 0, 0, 0);
  }

#pragma unroll
  for (int i = 0; i < 4; i++)
#pragma unroll
    for (int j = 0; j < 4; j++)
#pragma unroll
      for (int r = 0; r < 4; r++) {
        size_t row = arow0 + wm * 64 + i * 16 + lhi * 4 + r;
        size_t col = brow0 + wn * 64 + j * 16 + llo;
        float v = acc[i][j][r];
        if constexpr (sizeof(OT) == 2) C[row * N + col] = f2bf(v);
        else                           C[row * N + col] = v;
      }
}

// ---------------- flash attention, causal GQA ----------------
// grid: (NHEADS, SEQ/64); block 256 = 4 waves x 16 q-rows; qt reversed.
// Double-buffered K/V: prefetch tile t+1 (K via global_load_lds, V via regs)
// before computing tile t; V regs written to LDS after compute. Defer-max (T13).
__global__ __launch_bounds__(256, 2) void attn_fwd(const short* __restrict__ qkv,
                                                   short* __restrict__ aout) {
  const int qt = gridDim.y - 1 - blockIdx.y;
  const int h = blockIdx.x;
  const int kvh = h >> 2, g = h & 3;
  const int tid = threadIdx.x;
  const int wave = tid >> 6, lane = tid & 63;
  const int lhi = lane >> 4, llo = lane & 15;

  __shared__ __align__(16) short Ksm[2][64 * 128];   // XOR-swizzled (chunk ^= row&7)
  __shared__ __align__(16) short Vsm[2][64 * 128];   // subtiled [k/4][d/16][4][16]
  __shared__ __align__(16) short Psm[4][16 * 72];

  const float scale = 0.08838834764831845f;

  const int qrow = qt * 64 + wave * 16 + llo;
  const short* qbase = qkv + (size_t)qrow * QKV_LD + (kvh * 6 + g) * HD;
  short8 qf[4];
#pragma unroll
  for (int kk = 0; kk < 4; kk++) qf[kk] = *(const short8*)(qbase + kk * 32 + lhi * 8);

  f32x4 o[8] = {};
  float mrow[4], lrow[4];
#pragma unroll
  for (int r = 0; r < 4; r++) { mrow[r] = -1e30f; lrow[r] = 0.f; }

  const short* Kg = qkv + (kvh * 6 + 4) * HD;
  const short* Vg = qkv + (kvh * 6 + 5) * HD;

  // staging index helpers
  const int k_row = lhi;                 // + call*4
  const int v_vr = tid >> 4, v_vc = tid & 15;  // + c*16 rows

  auto STAGE_K = [&](int t, int buf) {
#pragma unroll
    for (int c = 0; c < 4; c++) {
      const int call = wave * 4 + c;
      const int row = call * 4 + k_row;
      const int sc = llo ^ (row & 7);
      __builtin_amdgcn_global_load_lds(
          (const __attribute__((address_space(1))) uint32_t*)(Kg + (size_t)(t * 64 + row) * QKV_LD + sc * 8),
          (__attribute__((address_space(3))) uint32_t*)(&Ksm[buf][0] + call * 512), 16, 0, 0);
    }
  };
  short8 vreg[4];
  auto LOAD_V = [&](int t) {
#pragma unroll
    for (int c = 0; c < 4; c++) {
      const int vr = c * 16 + v_vr;
      vreg[c] = *(const short8*)(Vg + (size_t)(t * 64 + vr) * QKV_LD + v_vc * 8);
    }
  };
  auto WRITE_V = [&](int buf) {
#pragma unroll
    for (int c = 0; c < 4; c++) {
      const int vr = c * 16 + v_vr;
      *(short8*)(&Vsm[buf][0] + ((vr >> 2) * 8 + (v_vc >> 1)) * 64 + (vr & 3) * 16 + (v_vc & 1) * 8) = vreg[c];
    }
  };

  const uint32_t vlane0 = (uint32_t)(uintptr_t)(__attribute__((address_space(3))) short*)(&Vsm[0][0])
                          + (uint32_t)(lhi * 2048 + llo * 8);

  // prologue: stage tile 0 into buf 0
  STAGE_K(0, 0);
  LOAD_V(0);
  asm volatile("s_waitcnt vmcnt(0)" ::: "memory");
  WRITE_V(0);
  __syncthreads();

  const int ntiles = qt + 1;
  for (int t = 0; t < ntiles; t++) {
    const int cur = t & 1, nxt = cur ^ 1;
    const bool pf = (t + 1 < ntiles);
    // prefetch next tile (K -> LDS[nxt] via DMA, V -> regs); latency hides under compute
    if (pf) { STAGE_K(t + 1, nxt); LOAD_V(t + 1); }

    // S = Q K^T from Ksm[cur]
    const short* Kc = &Ksm[cur][0];
    f32x4 s[4] = {};
#pragma unroll
    for (int n = 0; n < 4; n++) {
#pragma unroll
      for (int kk = 0; kk < 4; kk++) {
        const int krow = n * 16 + llo;
        const int ch = (kk * 4 + lhi) ^ (krow & 7);
        short8 kf = *(const short8*)(Kc + krow * 128 + ch * 8);
        s[n] = __builtin_amdgcn_mfma_f32_16x16x32_bf16(qf[kk], kf, s[n], 0, 0, 0);
      }
    }

    float sv[4][4];
    const bool diag = (t == qt);
#pragma unroll
    for (int n = 0; n < 4; n++)
#pragma unroll
      for (int r = 0; r < 4; r++) {
        float x = s[n][r] * scale;
        if (diag && (n * 16 + llo > wave * 16 + lhi * 4 + r)) x = -1e30f;
        sv[n][r] = x;
      }

    // online softmax with defer-max (T13): skip rescale while max growth <= 8
    float rm4[4];
#pragma unroll
    for (int r = 0; r < 4; r++) {
      float rm = fmaxf(fmaxf(sv[0][r], sv[1][r]), fmaxf(sv[2][r], sv[3][r]));
#pragma unroll
      for (int msk = 1; msk < 16; msk <<= 1) rm = fmaxf(rm, __shfl_xor(rm, msk));
      rm4[r] = rm;
    }
    bool need = false;
#pragma unroll
    for (int r = 0; r < 4; r++) need = need || (rm4[r] > mrow[r] + 8.0f);
    if (__any(need)) {
#pragma unroll
      for (int r = 0; r < 4; r++) {
        const float mnew = fmaxf(mrow[r], rm4[r]);
        const float a = __expf(mrow[r] - mnew);
        mrow[r] = mnew;
        lrow[r] *= a;
#pragma unroll
        for (int nn = 0; nn < 8; nn++) o[nn][r] *= a;
      }
    }
#pragma unroll
    for (int r = 0; r < 4; r++) {
      float rs = 0.f;
#pragma unroll
      for (int n = 0; n < 4; n++) {
        float p = __expf(sv[n][r] - mrow[r]);
        sv[n][r] = p;
        rs += p;
      }
#pragma unroll
      for (int msk = 1; msk < 16; msk <<= 1) rs += __shfl_xor(rs, msk);
      lrow[r] += rs;
    }

    // P -> LDS (bf16), wave-local
    short* P = &Psm[wave][0];
#pragma unroll
    for (int n = 0; n < 4; n++)
#pragma unroll
      for (int r = 0; r < 4; r++)
        P[(lhi * 4 + r) * 72 + n * 16 + llo] = f2bf(sv[n][r]);

    // PV from Vsm[cur] via cooperative transpose reads
    short8 pa0 = *(const short8*)(P + llo * 72 + lhi * 8);
    short8 pa1 = *(const short8*)(P + llo * 72 + 32 + lhi * 8);
    const uint32_t vlane = vlane0 + (uint32_t)(cur * 16384);
#pragma unroll
    for (int ks = 0; ks < 2; ks++) {
      uint2v vr_[8][2];
#pragma unroll
      for (int nn = 0; nn < 8; nn++)
#pragma unroll
        for (int hh = 0; hh < 2; hh++) {
          uint32_t a = vlane + (uint32_t)(ks * 8192 + hh * 1024 + nn * 128);
          asm volatile("ds_read_b64_tr_b16 %0, %1" : "=v"(vr_[nn][hh]) : "v"(a));
        }
      asm volatile("s_waitcnt lgkmcnt(0)" ::: "memory");
      __builtin_amdgcn_sched_barrier(0);
      const short8 pa = ks ? pa1 : pa0;
#pragma unroll
      for (int nn = 0; nn < 8; nn++) {
        int4v tv;
        tv[0] = (int)vr_[nn][0][0]; tv[1] = (int)vr_[nn][0][1];
        tv[2] = (int)vr_[nn][1][0]; tv[3] = (int)vr_[nn][1][1];
        o[nn] = __builtin_amdgcn_mfma_f32_16x16x32_bf16(pa, __builtin_bit_cast(short8, tv), o[nn], 0, 0, 0);
      }
    }

    // tail: commit prefetched V into LDS[nxt]; make buffers ready for t+1
    if (pf) {
      asm volatile("s_waitcnt vmcnt(0)" ::: "memory");  // K DMA + V regs landed
      __syncthreads();                                   // all waves done with buf[nxt] reads (tile t-1)
      WRITE_V(nxt);
      __syncthreads();                                   // stage t+1 visible
    }
  }

#pragma unroll
  for (int nn = 0; nn < 8; nn++)
#pragma unroll
    for (int r = 0; r < 4; r++) {
      const size_t row = qt * 64 + wave * 16 + lhi * 4 + r;
      const size_t col = (size_t)h * HD + nn * 16 + llo;
      aout[row * OUT_LD + col] = f2bf(o[nn][r] / lrow[r]);
    }
}

// ---------------- launch ----------------
extern "C" void kernel_launch(void* const* d_in, const int* in_sizes, int n_in,
                              void* d_out, int out_size, void* d_ws, size_t ws_size,
                              hipStream_t stream) {
  const float* tokens = (const float*)d_in[0];
  const float* wqkv   = (const float*)d_in[1];
  const float* wproj  = (const float*)d_in[2];
  float* out = (float*)d_out;

  short* tok_bf   = (short*)d_ws;
  short* wqkv_bf  = tok_bf   + (size_t)SEQ * HIDDEN;
  short* wproj_bf = wqkv_bf  + (size_t)QKV_LD * HIDDEN;
  short* qkv_bf   = wproj_bf + (size_t)HIDDEN * OUT_LD;
  short* attn_bf  = qkv_bf   + (size_t)SEQ * QKV_LD;

  cast_kernel<<<2048, 256, 0, stream>>>(tokens, tok_bf, SEQ * HIDDEN / 4);
  cast_kernel<<<2048, 256, 0, stream>>>(wqkv, wqkv_bf, QKV_LD * HIDDEN / 4);
  cast_kernel<<<2048, 256, 0, stream>>>(wproj, wproj_bf, HIDDEN * OUT_LD / 4);

  gemm256<short><<<192, 512, 0, stream>>>(tok_bf, wqkv_bf, qkv_bf, SEQ, QKV_LD, HIDDEN, QKV_LD / 256);

  attn_fwd<<<dim3(NHEADS, SEQ / 64), 256, 0, stream>>>(qkv_bf, attn_bf);

  gemm_bt<float><<<dim3(SEQ / 128, OUT_LD / 128), 256, 0, stream>>>(
      attn_bf, wproj_bf, out, SEQ, OUT_LD, HIDDEN);
}

// Round 7
// 338.915 us; speedup vs baseline: 1.6091x; 1.1034x over previous
//
#include <hip/hip_runtime.h>
#include <hip/hip_bf16.h>
#include <stdint.h>

#define SEQ 2048
#define HIDDEN 4096
#define NHEADS 32
#define HD 128
#define QKV_LD 6144
#define OUT_LD 4096

typedef __attribute__((ext_vector_type(8))) short short8;
typedef __attribute__((ext_vector_type(4))) short short4v;
typedef __attribute__((ext_vector_type(4))) float f32x4;
typedef __attribute__((ext_vector_type(4))) int int4v;
typedef __attribute__((ext_vector_type(2))) unsigned int uint2v;
typedef __attribute__((ext_vector_type(4))) float float4v;

__device__ __forceinline__ short f2bf(float f) {
  uint32_t u = __builtin_bit_cast(uint32_t, f);
  u += 0x7fff + ((u >> 16) & 1);   // RNE
  return (short)(u >> 16);
}

// ---------------- cast fp32 -> bf16 ----------------
__global__ void cast_kernel(const float* __restrict__ in, short* __restrict__ out, int n4) {
  int stride = gridDim.x * blockDim.x;
  for (int i = blockIdx.x * blockDim.x + threadIdx.x; i < n4; i += stride) {
    float4v v = ((const float4v*)in)[i];
    short4v o;
    o[0] = f2bf(v[0]); o[1] = f2bf(v[1]); o[2] = f2bf(v[2]); o[3] = f2bf(v[3]);
    ((short4v*)out)[i] = o;
  }
}

// ======== 256 x (64*NBF) 8-phase GEMM: C[M][N] = A[M][K] * B[N][K]^T ========
// 512 thr = 8 waves (2M x 4N). BK=64, double-buffered LDS, chunk^=row&7 swizzle.
// Per K-tile: 4 phases over M-quarters; ph0 reads all B + A01, ph1 A23+A45,
// ph2 A67, ph3 stages the next same-parity tile (4+NBF calls) and gates
// vmcnt(4+NBF) -> every staged tile has 4 phases in flight before its gate.
template <typename OT, int NBF>
__global__ __launch_bounds__(512, 2) void gemm256b(const short* __restrict__ A,
                                                   const short* __restrict__ B,
                                                   OT* __restrict__ C,
                                                   int M, int N, int K, int NT) {
  __shared__ __align__(16) short lds[32768 + NBF * 8192];  // A: 2x16384, B: 2x NBF*4096
  const int tid = threadIdx.x;
  const int w = tid >> 6, lane = tid & 63;
  const int wr = w >> 2, wc = w & 3;
  const int llo = lane & 15, lhi = lane >> 4;

  // T1 bijective XCD swizzle (nwg % 8 == 0)
  const int nwg = gridDim.x;
  const int cpx = nwg >> 3;
  const int work = ((int)blockIdx.x & 7) * cpx + ((int)blockIdx.x >> 3);
  const int mt = work / NT, nt = work % NT;
  const size_t arow0 = (size_t)mt * 256, brow0 = (size_t)nt * (NBF * 64);
  const short* Ab = A + arow0 * K;
  const short* Bb = B + brow0 * K;

  f32x4 acc[8][NBF] = {};

  // one call = 512 thr x 16B = 8KB = 64 rows; dst is wave-uniform (w only)
  auto STAGE_A = [&](int kt, int j) {
    const int bufd = kt & 1;
    const int r0 = (j << 6) + (w << 3);
    const int row = r0 + (lane >> 3);
    const short* src = Ab + (size_t)row * K + (kt << 6) + (((lane & 7) ^ (row & 7)) << 3);
    short* dst = lds + (bufd << 14) + r0 * 64;
    __builtin_amdgcn_global_load_lds(
        (const __attribute__((address_space(1))) uint32_t*)src,
        (__attribute__((address_space(3))) uint32_t*)dst, 16, 0, 0);
  };
  auto STAGE_B = [&](int kt, int j) {
    const int bufd = kt & 1;
    const int r0 = (j << 6) + (w << 3);
    const int row = r0 + (lane >> 3);
    const short* src = Bb + (size_t)row * K + (kt << 6) + (((lane & 7) ^ (row & 7)) << 3);
    short* dst = lds + 32768 + bufd * (NBF << 12) + r0 * 64;
    __builtin_amdgcn_global_load_lds(
        (const __attribute__((address_space(1))) uint32_t*)src,
        (__attribute__((address_space(3))) uint32_t*)dst, 16, 0, 0);
  };
  auto STAGE = [&](int kt) {
#pragma unroll
    for (int j = 0; j < 4; j++) STAGE_A(kt, j);
#pragma unroll
    for (int j = 0; j < NBF; j++) STAGE_B(kt, j);
  };

  auto LDA = [&](int bufd, int m, int kk) -> short8 {
    const int row = (wr << 7) + (m << 4) + llo;
    const int ch = ((kk << 2) + lhi) ^ (row & 7);
    return *(const short8*)(lds + (bufd << 14) + row * 64 + (ch << 3));
  };
  auto LDB = [&](int bufd, int n, int kk) -> short8 {
    const int row = wc * (NBF << 4) + (n << 4) + llo;
    const int ch = ((kk << 2) + lhi) ^ (row & 7);
    return *(const short8*)(lds + 32768 + bufd * (NBF << 12) + row * 64 + (ch << 3));
  };

  // one buffer-half = 4 phases; ktStage staged at ph3 when doStage
  auto HALF = [&](int bufd, int ktStage, bool doStage, bool gateFinal) {
    short8 b_[NBF][2], a_[2][2], an_[2][2], an2_[2][2];
    // ---- ph0: all B + A01 ----
#pragma unroll
    for (int n = 0; n < NBF; n++) { b_[n][0] = LDB(bufd, n, 0); b_[n][1] = LDB(bufd, n, 1); }
#pragma unroll
    for (int mi = 0; mi < 2; mi++) { a_[mi][0] = LDA(bufd, mi, 0); a_[mi][1] = LDA(bufd, mi, 1); }
    __builtin_amdgcn_s_barrier();
    asm volatile("s_waitcnt lgkmcnt(0)" ::: "memory");
    __builtin_amdgcn_sched_barrier(0);
    __builtin_amdgcn_s_setprio(1);
#pragma unroll
    for (int mi = 0; mi < 2; mi++)
#pragma unroll
      for (int n = 0; n < NBF; n++)
#pragma unroll
        for (int kk = 0; kk < 2; kk++)
          acc[mi][n] = __builtin_amdgcn_mfma_f32_16x16x32_bf16(a_[mi][kk], b_[n][kk], acc[mi][n], 0, 0, 0);
    __builtin_amdgcn_s_setprio(0);
    __builtin_amdgcn_s_barrier();
    // ---- ph1: read A23 (used now) + A45 (used ph2) ----
#pragma unroll
    for (int mi = 0; mi < 2; mi++) {
      an_[mi][0] = LDA(bufd, 2 + mi, 0);  an_[mi][1] = LDA(bufd, 2 + mi, 1);
      an2_[mi][0] = LDA(bufd, 4 + mi, 0); an2_[mi][1] = LDA(bufd, 4 + mi, 1);
    }
    __builtin_amdgcn_s_barrier();
    asm volatile("s_waitcnt lgkmcnt(0)" ::: "memory");
    __builtin_amdgcn_sched_barrier(0);
    __builtin_amdgcn_s_setprio(1);
#pragma unroll
    for (int mi = 0; mi < 2; mi++)
#pragma unroll
      for (int n = 0; n < NBF; n++)
#pragma unroll
        for (int kk = 0; kk < 2; kk++)
          acc[2 + mi][n] = __builtin_amdgcn_mfma_f32_16x16x32_bf16(an_[mi][kk], b_[n][kk], acc[2 + mi][n], 0, 0, 0);
    __builtin_amdgcn_s_setprio(0);
    __builtin_amdgcn_s_barrier();
    // ---- ph2: read A67; compute A45 (last LDS reads of this buffer) ----
#pragma unroll
    for (int mi = 0; mi < 2; mi++) { a_[mi][0] = LDA(bufd, 6 + mi, 0); a_[mi][1] = LDA(bufd, 6 + mi, 1); }
    __builtin_amdgcn_s_barrier();
    asm volatile("s_waitcnt lgkmcnt(0)" ::: "memory");
    __builtin_amdgcn_sched_barrier(0);
    __builtin_amdgcn_s_setprio(1);
#pragma unroll
    for (int mi = 0; mi < 2; mi++)
#pragma unroll
      for (int n = 0; n < NBF; n++)
#pragma unroll
        for (int kk = 0; kk < 2; kk++)
          acc[4 + mi][n] = __builtin_amdgcn_mfma_f32_16x16x32_bf16(an2_[mi][kk], b_[n][kk], acc[4 + mi][n], 0, 0, 0);
    __builtin_amdgcn_s_setprio(0);
    __builtin_amdgcn_s_barrier();
    // ---- ph3: no reads; stage refill of this buffer; compute A67; gate other buffer ----
    if (doStage) STAGE(ktStage);
    __builtin_amdgcn_s_barrier();
    __builtin_amdgcn_sched_barrier(0);
    __builtin_amdgcn_s_setprio(1);
#pragma unroll
    for (int mi = 0; mi < 2; mi++)
#pragma unroll
      for (int n = 0; n < NBF; n++)
#pragma unroll
        for (int kk = 0; kk < 2; kk++)
          acc[6 + mi][n] = __builtin_amdgcn_mfma_f32_16x16x32_bf16(a_[mi][kk], b_[n][kk], acc[6 + mi][n], 0, 0, 0);
    __builtin_amdgcn_s_setprio(0);
    if (doStage) {
      if constexpr (NBF == 3) asm volatile("s_waitcnt vmcnt(7)" ::: "memory");
      else                    asm volatile("s_waitcnt vmcnt(6)" ::: "memory");
    } else if (gateFinal) {
      asm volatile("s_waitcnt vmcnt(0)" ::: "memory");
    }
    __builtin_amdgcn_s_barrier();
  };

  // ---- prologue: stage tiles 0 and 1, gate tile 0 ----
  STAGE(0);
  STAGE(1);
  if constexpr (NBF == 3) asm volatile("s_waitcnt vmcnt(7)" ::: "memory");
  else                    asm volatile("s_waitcnt vmcnt(6)" ::: "memory");
  __builtin_amdgcn_s_barrier();

  const int NIT = (K >> 6) >> 1;
  for (int it = 0; it < NIT; ++it) {
    const bool stN = (it + 1 < NIT);
    HALF(0, 2 * it + 2, stN, !stN);
    HALF(1, 2 * it + 3, stN, false);
  }

  // ---- epilogue ----
#pragma unroll
  for (int m = 0; m < 8; m++)
#pragma unroll
    for (int n = 0; n < NBF; n++)
#pragma unroll
      for (int r = 0; r < 4; r++) {
        const size_t row = arow0 + (wr << 7) + (m << 4) + (lhi << 2) + r;
        const size_t col = brow0 + wc * (NBF << 4) + (n << 4) + llo;
        const float v = acc[m][n][r];
        if constexpr (sizeof(OT) == 2) C[row * N + col] = f2bf(v);
        else                           C[row * N + col] = v;
      }
}

// ---------------- flash attention, causal GQA ----------------
// grid: (NHEADS, SEQ/64); block 256 = 4 waves x 16 q-rows; qt reversed.
// Double-buffered K/V prefetch; defer-max (T13).
__global__ __launch_bounds__(256, 2) void attn_fwd(const short* __restrict__ qkv,
                                                   short* __restrict__ aout) {
  const int qt = gridDim.y - 1 - blockIdx.y;
  const int h = blockIdx.x;
  const int kvh = h >> 2, g = h & 3;
  const int tid = threadIdx.x;
  const int wave = tid >> 6, lane = tid & 63;
  const int lhi = lane >> 4, llo = lane & 15;

  __shared__ __align__(16) short Ksm[2][64 * 128];
  __shared__ __align__(16) short Vsm[2][64 * 128];
  __shared__ __align__(16) short Psm[4][16 * 72];

  const float scale = 0.08838834764831845f;

  const int qrow = qt * 64 + wave * 16 + llo;
  const short* qbase = qkv + (size_t)qrow * QKV_LD + (kvh * 6 + g) * HD;
  short8 qf[4];
#pragma unroll
  for (int kk = 0; kk < 4; kk++) qf[kk] = *(const short8*)(qbase + kk * 32 + lhi * 8);

  f32x4 o[8] = {};
  float mrow[4], lrow[4];
#pragma unroll
  for (int r = 0; r < 4; r++) { mrow[r] = -1e30f; lrow[r] = 0.f; }

  const short* Kg = qkv + (kvh * 6 + 4) * HD;
  const short* Vg = qkv + (kvh * 6 + 5) * HD;

  const int k_row = lhi;
  const int v_vr = tid >> 4, v_vc = tid & 15;

  auto STAGE_K = [&](int t, int buf) {
#pragma unroll
    for (int c = 0; c < 4; c++) {
      const int call = wave * 4 + c;
      const int row = call * 4 + k_row;
      const int sc = llo ^ (row & 7);
      __builtin_amdgcn_global_load_lds(
          (const __attribute__((address_space(1))) uint32_t*)(Kg + (size_t)(t * 64 + row) * QKV_LD + sc * 8),
          (__attribute__((address_space(3))) uint32_t*)(&Ksm[buf][0] + call * 512), 16, 0, 0);
    }
  };
  short8 vreg[4];
  auto LOAD_V = [&](int t) {
#pragma unroll
    for (int c = 0; c < 4; c++) {
      const int vr = c * 16 + v_vr;
      vreg[c] = *(const short8*)(Vg + (size_t)(t * 64 + vr) * QKV_LD + v_vc * 8);
    }
  };
  auto WRITE_V = [&](int buf) {
#pragma unroll
    for (int c = 0; c < 4; c++) {
      const int vr = c * 16 + v_vr;
      *(short8*)(&Vsm[buf][0] + ((vr >> 2) * 8 + (v_vc >> 1)) * 64 + (vr & 3) * 16 + (v_vc & 1) * 8) = vreg[c];
    }
  };

  const uint32_t vlane0 = (uint32_t)(uintptr_t)(__attribute__((address_space(3))) short*)(&Vsm[0][0])
                          + (uint32_t)(lhi * 2048 + llo * 8);

  STAGE_K(0, 0);
  LOAD_V(0);
  asm volatile("s_waitcnt vmcnt(0)" ::: "memory");
  WRITE_V(0);
  __syncthreads();

  const int ntiles = qt + 1;
  for (int t = 0; t < ntiles; t++) {
    const int cur = t & 1, nxt = cur ^ 1;
    const bool pf = (t + 1 < ntiles);
    if (pf) { STAGE_K(t + 1, nxt); LOAD_V(t + 1); }

    const short* Kc = &Ksm[cur][0];
    f32x4 s[4] = {};
#pragma unroll
    for (int n = 0; n < 4; n++) {
#pragma unroll
      for (int kk = 0; kk < 4; kk++) {
        const int krow = n * 16 + llo;
        const int ch = (kk * 4 + lhi) ^ (krow & 7);
        short8 kf = *(const short8*)(Kc + krow * 128 + ch * 8);
        s[n] = __builtin_amdgcn_mfma_f32_16x16x32_bf16(qf[kk], kf, s[n], 0, 0, 0);
      }
    }

    float sv[4][4];
    const bool diag = (t == qt);
#pragma unroll
    for (int n = 0; n < 4; n++)
#pragma unroll
      for (int r = 0; r < 4; r++) {
        float x = s[n][r] * scale;
        if (diag && (n * 16 + llo > wave * 16 + lhi * 4 + r)) x = -1e30f;
        sv[n][r] = x;
      }

    float rm4[4];
#pragma unroll
    for (int r = 0; r < 4; r++) {
      float rm = fmaxf(fmaxf(sv[0][r], sv[1][r]), fmaxf(sv[2][r], sv[3][r]));
#pragma unroll
      for (int msk = 1; msk < 16; msk <<= 1) rm = fmaxf(rm, __shfl_xor(rm, msk));
      rm4[r] = rm;
    }
    bool need = false;
#pragma unroll
    for (int r = 0; r < 4; r++) need = need || (rm4[r] > mrow[r] + 8.0f);
    if (__any(need)) {
#pragma unroll
      for (int r = 0; r < 4; r++) {
        const float mnew = fmaxf(mrow[r], rm4[r]);
        const float a = __expf(mrow[r] - mnew);
        mrow[r] = mnew;
        lrow[r] *= a;
#pragma unroll
        for (int nn = 0; nn < 8; nn++) o[nn][r] *= a;
      }
    }
#pragma unroll
    for (int r = 0; r < 4; r++) {
      float rs = 0.f;
#pragma unroll
      for (int n = 0; n < 4; n++) {
        float p = __expf(sv[n][r] - mrow[r]);
        sv[n][r] = p;
        rs += p;
      }
#pragma unroll
      for (int msk = 1; msk < 16; msk <<= 1) rs += __shfl_xor(rs, msk);
      lrow[r] += rs;
    }

    short* P = &Psm[wave][0];
#pragma unroll
    for (int n = 0; n < 4; n++)
#pragma unroll
      for (int r = 0; r < 4; r++)
        P[(lhi * 4 + r) * 72 + n * 16 + llo] = f2bf(sv[n][r]);

    short8 pa0 = *(const short8*)(P + llo * 72 + lhi * 8);
    short8 pa1 = *(const short8*)(P + llo * 72 + 32 + lhi * 8);
    const uint32_t vlane = vlane0 + (uint32_t)(cur * 16384);
#pragma unroll
    for (int ks = 0; ks < 2; ks++) {
      uint2v vr_[8][2];
#pragma unroll
      for (int nn = 0; nn < 8; nn++)
#pragma unroll
        for (int hh = 0; hh < 2; hh++) {
          uint32_t a = vlane + (uint32_t)(ks * 8192 + hh * 1024 + nn * 128);
          asm volatile("ds_read_b64_tr_b16 %0, %1" : "=v"(vr_[nn][hh]) : "v"(a));
        }
      asm volatile("s_waitcnt lgkmcnt(0)" ::: "memory");
      __builtin_amdgcn_sched_barrier(0);
      const short8 pa = ks ? pa1 : pa0;
#pragma unroll
      for (int nn = 0; nn < 8; nn++) {
        int4v tv;
        tv[0] = (int)vr_[nn][0][0]; tv[1] = (int)vr_[nn][0][1];
        tv[2] = (int)vr_[nn][1][0]; tv[3] = (int)vr_[nn][1][1];
        o[nn] = __builtin_amdgcn_mfma_f32_16x16x32_bf16(pa, __builtin_bit_cast(short8, tv), o[nn], 0, 0, 0);
      }
    }

    if (pf) {
      asm volatile("s_waitcnt vmcnt(0)" ::: "memory");
      __syncthreads();
      WRITE_V(nxt);
      __syncthreads();
    }
  }

#pragma unroll
  for (int nn = 0; nn < 8; nn++)
#pragma unroll
    for (int r = 0; r < 4; r++) {
      const size_t row = qt * 64 + wave * 16 + lhi * 4 + r;
      const size_t col = (size_t)h * HD + nn * 16 + llo;
      aout[row * OUT_LD + col] = f2bf(o[nn][r] / lrow[r]);
    }
}

// ---------------- launch ----------------
extern "C" void kernel_launch(void* const* d_in, const int* in_sizes, int n_in,
                              void* d_out, int out_size, void* d_ws, size_t ws_size,
                              hipStream_t stream) {
  const float* tokens = (const float*)d_in[0];
  const float* wqkv   = (const float*)d_in[1];
  const float* wproj  = (const float*)d_in[2];
  float* out = (float*)d_out;

  short* tok_bf   = (short*)d_ws;
  short* wqkv_bf  = tok_bf   + (size_t)SEQ * HIDDEN;
  short* wproj_bf = wqkv_bf  + (size_t)QKV_LD * HIDDEN;
  short* qkv_bf   = wproj_bf + (size_t)HIDDEN * OUT_LD;
  short* attn_bf  = qkv_bf   + (size_t)SEQ * QKV_LD;

  cast_kernel<<<2048, 256, 0, stream>>>(tokens, tok_bf, SEQ * HIDDEN / 4);
  cast_kernel<<<2048, 256, 0, stream>>>(wqkv, wqkv_bf, QKV_LD * HIDDEN / 4);
  cast_kernel<<<2048, 256, 0, stream>>>(wproj, wproj_bf, HIDDEN * OUT_LD / 4);

  // QKV: 256x192 tiles -> 8 x 32 = 256 workgroups (perfect fill)
  gemm256b<short, 3><<<256, 512, 0, stream>>>(tok_bf, wqkv_bf, qkv_bf, SEQ, QKV_LD, HIDDEN, QKV_LD / 192);

  attn_fwd<<<dim3(NHEADS, SEQ / 64), 256, 0, stream>>>(qkv_bf, attn_bf);

  // proj: 256x128 tiles -> 8 x 32 = 256 workgroups (perfect fill)
  gemm256b<float, 2><<<256, 512, 0, stream>>>(attn_bf, wproj_bf, out, SEQ, OUT_LD, HIDDEN, OUT_LD / 128);
}

// Round 8
// 333.677 us; speedup vs baseline: 1.6344x; 1.0157x over previous
//
#include <hip/hip_runtime.h>
#include <hip/hip_bf16.h>
#include <stdint.h>

#define SEQ 2048
#define HIDDEN 4096
#define NHEADS 32
#define HD 128
#define QKV_LD 6144
#define OUT_LD 4096

typedef __attribute__((ext_vector_type(8))) short short8;
typedef __attribute__((ext_vector_type(4))) short short4v;
typedef __attribute__((ext_vector_type(4))) float f32x4;
typedef __attribute__((ext_vector_type(4))) int int4v;
typedef __attribute__((ext_vector_type(2))) unsigned int uint2v;
typedef __attribute__((ext_vector_type(4))) float float4v;

__device__ __forceinline__ short f2bf(float f) {
  uint32_t u = __builtin_bit_cast(uint32_t, f);
  u += 0x7fff + ((u >> 16) & 1);   // RNE
  return (short)(u >> 16);
}

// ---------------- cast fp32 -> bf16 ----------------
__global__ void cast_kernel(const float* __restrict__ in, short* __restrict__ out, int n4) {
  int stride = gridDim.x * blockDim.x;
  for (int i = blockIdx.x * blockDim.x + threadIdx.x; i < n4; i += stride) {
    float4v v = ((const float4v*)in)[i];
    short4v o;
    o[0] = f2bf(v[0]); o[1] = f2bf(v[1]); o[2] = f2bf(v[2]); o[3] = f2bf(v[3]);
    ((short4v*)out)[i] = o;
  }
}

// ======== 256 x (64*NBF) GEMM, 2-barrier K-tile: C = A[M][K] * B[N][K]^T ========
// 512 thr = 8 waves (2M x 4N). BK=64, double-buffered LDS, chunk^=row&7 swizzle.
// Per K-tile: one compiler-scheduled read+MFMA block (reads of A[m+1] overlap
// MFMA of A[m]), then {lgkm0, barrier, STAGE(kt+2), counted vmcnt, barrier}.
template <typename OT, int NBF>
__global__ __launch_bounds__(512, 2) void gemm256b(const short* __restrict__ A,
                                                   const short* __restrict__ B,
                                                   OT* __restrict__ C,
                                                   int M, int N, int K, int NT) {
  __shared__ __align__(16) short lds[32768 + NBF * 8192];  // A: 2x16384, B: 2x NBF*4096
  const int tid = threadIdx.x;
  const int w = tid >> 6, lane = tid & 63;
  const int wr = w >> 2, wc = w & 3;
  const int llo = lane & 15, lhi = lane >> 4;

  // T1 bijective XCD swizzle (nwg % 8 == 0)
  const int nwg = gridDim.x;
  const int cpx = nwg >> 3;
  const int work = ((int)blockIdx.x & 7) * cpx + ((int)blockIdx.x >> 3);
  const int mt = work / NT, nt = work % NT;
  const size_t arow0 = (size_t)mt * 256, brow0 = (size_t)nt * (NBF * 64);
  const short* Ab = A + arow0 * K;
  const short* Bb = B + brow0 * K;

  f32x4 acc[8][NBF] = {};

  // one call = 512 thr x 16B = 8KB = 64 rows; dst is wave-uniform (w only)
  auto STAGE_A = [&](int kt, int j) {
    const int bufd = kt & 1;
    const int r0 = (j << 6) + (w << 3);
    const int row = r0 + (lane >> 3);
    const short* src = Ab + (size_t)row * K + (kt << 6) + (((lane & 7) ^ (row & 7)) << 3);
    short* dst = lds + (bufd << 14) + r0 * 64;
    __builtin_amdgcn_global_load_lds(
        (const __attribute__((address_space(1))) uint32_t*)src,
        (__attribute__((address_space(3))) uint32_t*)dst, 16, 0, 0);
  };
  auto STAGE_B = [&](int kt, int j) {
    const int bufd = kt & 1;
    const int r0 = (j << 6) + (w << 3);
    const int row = r0 + (lane >> 3);
    const short* src = Bb + (size_t)row * K + (kt << 6) + (((lane & 7) ^ (row & 7)) << 3);
    short* dst = lds + 32768 + bufd * (NBF << 12) + r0 * 64;
    __builtin_amdgcn_global_load_lds(
        (const __attribute__((address_space(1))) uint32_t*)src,
        (__attribute__((address_space(3))) uint32_t*)dst, 16, 0, 0);
  };
  auto STAGE = [&](int kt) {
#pragma unroll
    for (int j = 0; j < 4; j++) STAGE_A(kt, j);
#pragma unroll
    for (int j = 0; j < NBF; j++) STAGE_B(kt, j);
  };

  auto LDA = [&](int bufd, int m, int kk) -> short8 {
    const int row = (wr << 7) + (m << 4) + llo;
    const int ch = ((kk << 2) + lhi) ^ (row & 7);
    return *(const short8*)(lds + (bufd << 14) + row * 64 + (ch << 3));
  };
  auto LDB = [&](int bufd, int n, int kk) -> short8 {
    const int row = wc * (NBF << 4) + (n << 4) + llo;
    const int ch = ((kk << 2) + lhi) ^ (row & 7);
    return *(const short8*)(lds + 32768 + bufd * (NBF << 12) + row * 64 + (ch << 3));
  };

  // ---- prologue: stage tiles 0 and 1, gate tile 0 ----
  STAGE(0);
  STAGE(1);
  if constexpr (NBF == 3) asm volatile("s_waitcnt vmcnt(7)" ::: "memory");
  else                    asm volatile("s_waitcnt vmcnt(6)" ::: "memory");
  __builtin_amdgcn_s_barrier();

  const int NKT = K >> 6;
  for (int kt = 0; kt < NKT; ++kt) {
    const int bufd = kt & 1;
    // B fragments for the whole tile
    short8 b_[NBF][2];
#pragma unroll
    for (int n = 0; n < NBF; n++) { b_[n][0] = LDB(bufd, n, 0); b_[n][1] = LDB(bufd, n, 1); }
    // m-major: compiler overlaps A-reads of m+1 with MFMA of m
#pragma unroll
    for (int m = 0; m < 8; m++) {
      short8 a0 = LDA(bufd, m, 0);
      short8 a1 = LDA(bufd, m, 1);
      __builtin_amdgcn_s_setprio(1);
#pragma unroll
      for (int n = 0; n < NBF; n++) {
        acc[m][n] = __builtin_amdgcn_mfma_f32_16x16x32_bf16(a0, b_[n][0], acc[m][n], 0, 0, 0);
        acc[m][n] = __builtin_amdgcn_mfma_f32_16x16x32_bf16(a1, b_[n][1], acc[m][n], 0, 0, 0);
      }
      __builtin_amdgcn_s_setprio(0);
    }
    asm volatile("s_waitcnt lgkmcnt(0)" ::: "memory");
    __builtin_amdgcn_s_barrier();            // all waves done reading bufd
    if (kt + 2 < NKT) STAGE(kt + 2);         // refill this buffer
    if (kt + 1 < NKT) {
      if (kt + 2 < NKT) {
        if constexpr (NBF == 3) asm volatile("s_waitcnt vmcnt(7)" ::: "memory");
        else                    asm volatile("s_waitcnt vmcnt(6)" ::: "memory");
      } else {
        asm volatile("s_waitcnt vmcnt(0)" ::: "memory");
      }
      __builtin_amdgcn_s_barrier();          // next tile's data visible
    }
  }

  // ---- epilogue ----
#pragma unroll
  for (int m = 0; m < 8; m++)
#pragma unroll
    for (int n = 0; n < NBF; n++)
#pragma unroll
      for (int r = 0; r < 4; r++) {
        const size_t row = arow0 + (wr << 7) + (m << 4) + (lhi << 2) + r;
        const size_t col = brow0 + wc * (NBF << 4) + (n << 4) + llo;
        const float v = acc[m][n][r];
        if constexpr (sizeof(OT) == 2) C[row * N + col] = f2bf(v);
        else                           C[row * N + col] = v;
      }
}

// ---------------- flash attention, causal GQA ----------------
// grid: (NHEADS, SEQ/64); block 256 = 4 waves x 16 q-rows; qt reversed.
// Double-buffered K/V prefetch; defer-max (T13).
__global__ __launch_bounds__(256, 2) void attn_fwd(const short* __restrict__ qkv,
                                                   short* __restrict__ aout) {
  const int qt = gridDim.y - 1 - blockIdx.y;
  const int h = blockIdx.x;
  const int kvh = h >> 2, g = h & 3;
  const int tid = threadIdx.x;
  const int wave = tid >> 6, lane = tid & 63;
  const int lhi = lane >> 4, llo = lane & 15;

  __shared__ __align__(16) short Ksm[2][64 * 128];
  __shared__ __align__(16) short Vsm[2][64 * 128];
  __shared__ __align__(16) short Psm[4][16 * 72];

  const float scale = 0.08838834764831845f;

  const int qrow = qt * 64 + wave * 16 + llo;
  const short* qbase = qkv + (size_t)qrow * QKV_LD + (kvh * 6 + g) * HD;
  short8 qf[4];
#pragma unroll
  for (int kk = 0; kk < 4; kk++) qf[kk] = *(const short8*)(qbase + kk * 32 + lhi * 8);

  f32x4 o[8] = {};
  float mrow[4], lrow[4];
#pragma unroll
  for (int r = 0; r < 4; r++) { mrow[r] = -1e30f; lrow[r] = 0.f; }

  const short* Kg = qkv + (kvh * 6 + 4) * HD;
  const short* Vg = qkv + (kvh * 6 + 5) * HD;

  const int k_row = lhi;
  const int v_vr = tid >> 4, v_vc = tid & 15;

  auto STAGE_K = [&](int t, int buf) {
#pragma unroll
    for (int c = 0; c < 4; c++) {
      const int call = wave * 4 + c;
      const int row = call * 4 + k_row;
      const int sc = llo ^ (row & 7);
      __builtin_amdgcn_global_load_lds(
          (const __attribute__((address_space(1))) uint32_t*)(Kg + (size_t)(t * 64 + row) * QKV_LD + sc * 8),
          (__attribute__((address_space(3))) uint32_t*)(&Ksm[buf][0] + call * 512), 16, 0, 0);
    }
  };
  short8 vreg[4];
  auto LOAD_V = [&](int t) {
#pragma unroll
    for (int c = 0; c < 4; c++) {
      const int vr = c * 16 + v_vr;
      vreg[c] = *(const short8*)(Vg + (size_t)(t * 64 + vr) * QKV_LD + v_vc * 8);
    }
  };
  auto WRITE_V = [&](int buf) {
#pragma unroll
    for (int c = 0; c < 4; c++) {
      const int vr = c * 16 + v_vr;
      *(short8*)(&Vsm[buf][0] + ((vr >> 2) * 8 + (v_vc >> 1)) * 64 + (vr & 3) * 16 + (v_vc & 1) * 8) = vreg[c];
    }
  };

  const uint32_t vlane0 = (uint32_t)(uintptr_t)(__attribute__((address_space(3))) short*)(&Vsm[0][0])
                          + (uint32_t)(lhi * 2048 + llo * 8);

  STAGE_K(0, 0);
  LOAD_V(0);
  asm volatile("s_waitcnt vmcnt(0)" ::: "memory");
  WRITE_V(0);
  __syncthreads();

  const int ntiles = qt + 1;
  for (int t = 0; t < ntiles; t++) {
    const int cur = t & 1, nxt = cur ^ 1;
    const bool pf = (t + 1 < ntiles);
    if (pf) { STAGE_K(t + 1, nxt); LOAD_V(t + 1); }

    const short* Kc = &Ksm[cur][0];
    f32x4 s[4] = {};
#pragma unroll
    for (int n = 0; n < 4; n++) {
#pragma unroll
      for (int kk = 0; kk < 4; kk++) {
        const int krow = n * 16 + llo;
        const int ch = (kk * 4 + lhi) ^ (krow & 7);
        short8 kf = *(const short8*)(Kc + krow * 128 + ch * 8);
        s[n] = __builtin_amdgcn_mfma_f32_16x16x32_bf16(qf[kk], kf, s[n], 0, 0, 0);
      }
    }

    float sv[4][4];
    const bool diag = (t == qt);
#pragma unroll
    for (int n = 0; n < 4; n++)
#pragma unroll
      for (int r = 0; r < 4; r++) {
        float x = s[n][r] * scale;
        if (diag && (n * 16 + llo > wave * 16 + lhi * 4 + r)) x = -1e30f;
        sv[n][r] = x;
      }

    float rm4[4];
#pragma unroll
    for (int r = 0; r < 4; r++) {
      float rm = fmaxf(fmaxf(sv[0][r], sv[1][r]), fmaxf(sv[2][r], sv[3][r]));
#pragma unroll
      for (int msk = 1; msk < 16; msk <<= 1) rm = fmaxf(rm, __shfl_xor(rm, msk));
      rm4[r] = rm;
    }
    bool need = false;
#pragma unroll
    for (int r = 0; r < 4; r++) need = need || (rm4[r] > mrow[r] + 8.0f);
    if (__any(need)) {
#pragma unroll
      for (int r = 0; r < 4; r++) {
        const float mnew = fmaxf(mrow[r], rm4[r]);
        const float a = __expf(mrow[r] - mnew);
        mrow[r] = mnew;
        lrow[r] *= a;
#pragma unroll
        for (int nn = 0; nn < 8; nn++) o[nn][r] *= a;
      }
    }
#pragma unroll
    for (int r = 0; r < 4; r++) {
      float rs = 0.f;
#pragma unroll
      for (int n = 0; n < 4; n++) {
        float p = __expf(sv[n][r] - mrow[r]);
        sv[n][r] = p;
        rs += p;
      }
#pragma unroll
      for (int msk = 1; msk < 16; msk <<= 1) rs += __shfl_xor(rs, msk);
      lrow[r] += rs;
    }

    short* P = &Psm[wave][0];
#pragma unroll
    for (int n = 0; n < 4; n++)
#pragma unroll
      for (int r = 0; r < 4; r++)
        P[(lhi * 4 + r) * 72 + n * 16 + llo] = f2bf(sv[n][r]);

    short8 pa0 = *(const short8*)(P + llo * 72 + lhi * 8);
    short8 pa1 = *(const short8*)(P + llo * 72 + 32 + lhi * 8);
    const uint32_t vlane = vlane0 + (uint32_t)(cur * 16384);
#pragma unroll
    for (int ks = 0; ks < 2; ks++) {
      uint2v vr_[8][2];
#pragma unroll
      for (int nn = 0; nn < 8; nn++)
#pragma unroll
        for (int hh = 0; hh < 2; hh++) {
          uint32_t a = vlane + (uint32_t)(ks * 8192 + hh * 1024 + nn * 128);
          asm volatile("ds_read_b64_tr_b16 %0, %1" : "=v"(vr_[nn][hh]) : "v"(a));
        }
      asm volatile("s_waitcnt lgkmcnt(0)" ::: "memory");
      __builtin_amdgcn_sched_barrier(0);
      const short8 pa = ks ? pa1 : pa0;
#pragma unroll
      for (int nn = 0; nn < 8; nn++) {
        int4v tv;
        tv[0] = (int)vr_[nn][0][0]; tv[1] = (int)vr_[nn][0][1];
        tv[2] = (int)vr_[nn][1][0]; tv[3] = (int)vr_[nn][1][1];
        o[nn] = __builtin_amdgcn_mfma_f32_16x16x32_bf16(pa, __builtin_bit_cast(short8, tv), o[nn], 0, 0, 0);
      }
    }

    if (pf) {
      asm volatile("s_waitcnt vmcnt(0)" ::: "memory");
      __syncthreads();
      WRITE_V(nxt);
      __syncthreads();
    }
  }

#pragma unroll
  for (int nn = 0; nn < 8; nn++)
#pragma unroll
    for (int r = 0; r < 4; r++) {
      const size_t row = qt * 64 + wave * 16 + lhi * 4 + r;
      const size_t col = (size_t)h * HD + nn * 16 + llo;
      aout[row * OUT_LD + col] = f2bf(o[nn][r] / lrow[r]);
    }
}

// ---------------- launch ----------------
extern "C" void kernel_launch(void* const* d_in, const int* in_sizes, int n_in,
                              void* d_out, int out_size, void* d_ws, size_t ws_size,
                              hipStream_t stream) {
  const float* tokens = (const float*)d_in[0];
  const float* wqkv   = (const float*)d_in[1];
  const float* wproj  = (const float*)d_in[2];
  float* out = (float*)d_out;

  short* tok_bf   = (short*)d_ws;
  short* wqkv_bf  = tok_bf   + (size_t)SEQ * HIDDEN;
  short* wproj_bf = wqkv_bf  + (size_t)QKV_LD * HIDDEN;
  short* qkv_bf   = wproj_bf + (size_t)HIDDEN * OUT_LD;
  short* attn_bf  = qkv_bf   + (size_t)SEQ * QKV_LD;

  cast_kernel<<<2048, 256, 0, stream>>>(tokens, tok_bf, SEQ * HIDDEN / 4);
  cast_kernel<<<2048, 256, 0, stream>>>(wqkv, wqkv_bf, QKV_LD * HIDDEN / 4);
  cast_kernel<<<2048, 256, 0, stream>>>(wproj, wproj_bf, HIDDEN * OUT_LD / 4);

  // QKV: 256x192 tiles -> 8 x 32 = 256 workgroups (perfect fill)
  gemm256b<short, 3><<<256, 512, 0, stream>>>(tok_bf, wqkv_bf, qkv_bf, SEQ, QKV_LD, HIDDEN, QKV_LD / 192);

  attn_fwd<<<dim3(NHEADS, SEQ / 64), 256, 0, stream>>>(qkv_bf, attn_bf);

  // proj: 256x128 tiles -> 8 x 32 = 256 workgroups (perfect fill)
  gemm256b<float, 2><<<256, 512, 0, stream>>>(attn_bf, wproj_bf, out, SEQ, OUT_LD, HIDDEN, OUT_LD / 128);
}

// Round 9
// 318.985 us; speedup vs baseline: 1.7097x; 1.0461x over previous
//
#include <hip/hip_runtime.h>
#include <hip/hip_bf16.h>
#include <stdint.h>

#define SEQ 2048
#define HIDDEN 4096
#define NHEADS 32
#define HD 128
#define QKV_LD 6144
#define OUT_LD 4096

typedef __attribute__((ext_vector_type(8))) short short8;
typedef __attribute__((ext_vector_type(4))) short short4v;
typedef __attribute__((ext_vector_type(4))) float f32x4;
typedef __attribute__((ext_vector_type(4))) int int4v;
typedef __attribute__((ext_vector_type(2))) unsigned int uint2v;
typedef __attribute__((ext_vector_type(4))) float float4v;

__device__ __forceinline__ short f2bf(float f) {
  uint32_t u = __builtin_bit_cast(uint32_t, f);
  u += 0x7fff + ((u >> 16) & 1);   // RNE
  return (short)(u >> 16);
}

// ---------------- cast fp32 -> bf16 ----------------
__global__ void cast_kernel(const float* __restrict__ in, short* __restrict__ out, int n4) {
  int stride = gridDim.x * blockDim.x;
  for (int i = blockIdx.x * blockDim.x + threadIdx.x; i < n4; i += stride) {
    float4v v = ((const float4v*)in)[i];
    short4v o;
    o[0] = f2bf(v[0]); o[1] = f2bf(v[1]); o[2] = f2bf(v[2]); o[3] = f2bf(v[3]);
    ((short4v*)out)[i] = o;
  }
}

// ======== 256 x (64*NBF) GEMM, 2-barrier K-tile: C = A[M][K] * B[N][K]^T ========
// 512 thr = 8 waves (2M x 4N). BK=64, double-buffered LDS, chunk^=row&7 swizzle.
template <typename OT, int NBF>
__global__ __launch_bounds__(512, 2) void gemm256b(const short* __restrict__ A,
                                                   const short* __restrict__ B,
                                                   OT* __restrict__ C,
                                                   int M, int N, int K, int NT) {
  __shared__ __align__(16) short lds[32768 + NBF * 8192];  // A: 2x16384, B: 2x NBF*4096
  const int tid = threadIdx.x;
  const int w = tid >> 6, lane = tid & 63;
  const int wr = w >> 2, wc = w & 3;
  const int llo = lane & 15, lhi = lane >> 4;

  // T1 bijective XCD swizzle (nwg % 8 == 0)
  const int nwg = gridDim.x;
  const int cpx = nwg >> 3;
  const int work = ((int)blockIdx.x & 7) * cpx + ((int)blockIdx.x >> 3);
  const int mt = work / NT, nt = work % NT;
  const size_t arow0 = (size_t)mt * 256, brow0 = (size_t)nt * (NBF * 64);
  const short* Ab = A + arow0 * K;
  const short* Bb = B + brow0 * K;

  f32x4 acc[8][NBF] = {};

  auto STAGE_A = [&](int kt, int j) {
    const int bufd = kt & 1;
    const int r0 = (j << 6) + (w << 3);
    const int row = r0 + (lane >> 3);
    const short* src = Ab + (size_t)row * K + (kt << 6) + (((lane & 7) ^ (row & 7)) << 3);
    short* dst = lds + (bufd << 14) + r0 * 64;
    __builtin_amdgcn_global_load_lds(
        (const __attribute__((address_space(1))) uint32_t*)src,
        (__attribute__((address_space(3))) uint32_t*)dst, 16, 0, 0);
  };
  auto STAGE_B = [&](int kt, int j) {
    const int bufd = kt & 1;
    const int r0 = (j << 6) + (w << 3);
    const int row = r0 + (lane >> 3);
    const short* src = Bb + (size_t)row * K + (kt << 6) + (((lane & 7) ^ (row & 7)) << 3);
    short* dst = lds + 32768 + bufd * (NBF << 12) + r0 * 64;
    __builtin_amdgcn_global_load_lds(
        (const __attribute__((address_space(1))) uint32_t*)src,
        (__attribute__((address_space(3))) uint32_t*)dst, 16, 0, 0);
  };
  auto STAGE = [&](int kt) {
#pragma unroll
    for (int j = 0; j < 4; j++) STAGE_A(kt, j);
#pragma unroll
    for (int j = 0; j < NBF; j++) STAGE_B(kt, j);
  };

  auto LDA = [&](int bufd, int m, int kk) -> short8 {
    const int row = (wr << 7) + (m << 4) + llo;
    const int ch = ((kk << 2) + lhi) ^ (row & 7);
    return *(const short8*)(lds + (bufd << 14) + row * 64 + (ch << 3));
  };
  auto LDB = [&](int bufd, int n, int kk) -> short8 {
    const int row = wc * (NBF << 4) + (n << 4) + llo;
    const int ch = ((kk << 2) + lhi) ^ (row & 7);
    return *(const short8*)(lds + 32768 + bufd * (NBF << 12) + row * 64 + (ch << 3));
  };

  // ---- prologue: stage tiles 0 and 1, gate tile 0 ----
  STAGE(0);
  STAGE(1);
  if constexpr (NBF == 3) asm volatile("s_waitcnt vmcnt(7)" ::: "memory");
  else                    asm volatile("s_waitcnt vmcnt(6)" ::: "memory");
  __builtin_amdgcn_s_barrier();

  const int NKT = K >> 6;
  for (int kt = 0; kt < NKT; ++kt) {
    const int bufd = kt & 1;
    short8 b_[NBF][2];
#pragma unroll
    for (int n = 0; n < NBF; n++) { b_[n][0] = LDB(bufd, n, 0); b_[n][1] = LDB(bufd, n, 1); }
#pragma unroll
    for (int m = 0; m < 8; m++) {
      short8 a0 = LDA(bufd, m, 0);
      short8 a1 = LDA(bufd, m, 1);
#pragma unroll
      for (int n = 0; n < NBF; n++) {
        acc[m][n] = __builtin_amdgcn_mfma_f32_16x16x32_bf16(a0, b_[n][0], acc[m][n], 0, 0, 0);
        acc[m][n] = __builtin_amdgcn_mfma_f32_16x16x32_bf16(a1, b_[n][1], acc[m][n], 0, 0, 0);
      }
    }
    asm volatile("s_waitcnt lgkmcnt(0)" ::: "memory");
    __builtin_amdgcn_s_barrier();            // all waves done reading bufd
    if (kt + 2 < NKT) STAGE(kt + 2);         // refill this buffer
    if (kt + 1 < NKT) {
      if (kt + 2 < NKT) {
        if constexpr (NBF == 3) asm volatile("s_waitcnt vmcnt(7)" ::: "memory");
        else                    asm volatile("s_waitcnt vmcnt(6)" ::: "memory");
      } else {
        asm volatile("s_waitcnt vmcnt(0)" ::: "memory");
      }
      __builtin_amdgcn_s_barrier();          // next tile's data visible
    }
  }

  // ---- epilogue ----
#pragma unroll
  for (int m = 0; m < 8; m++)
#pragma unroll
    for (int n = 0; n < NBF; n++)
#pragma unroll
      for (int r = 0; r < 4; r++) {
        const size_t row = arow0 + (wr << 7) + (m << 4) + (lhi << 2) + r;
        const size_t col = brow0 + wc * (NBF << 4) + (n << 4) + llo;
        const float v = acc[m][n][r];
        if constexpr (sizeof(OT) == 2) C[row * N + col] = f2bf(v);
        else                           C[row * N + col] = v;
      }
}

// ---------------- flash attention, causal GQA ----------------
// grid: (NHEADS, SEQ/128); block 512 = 8 waves x 16 q-rows; qt reversed.
// QBLK=128: each staged KV tile feeds 8 waves (2x the MFMA per staged byte).
// Double-buffered K/V prefetch; defer-max (T13).
__global__ __launch_bounds__(512) void attn_fwd(const short* __restrict__ qkv,
                                                short* __restrict__ aout) {
  const int qt = gridDim.y - 1 - blockIdx.y;          // 0..15, heavy blocks first
  const int h = blockIdx.x;
  const int kvh = h >> 2, g = h & 3;
  const int tid = threadIdx.x;
  const int wave = tid >> 6, lane = tid & 63;
  const int lhi = lane >> 4, llo = lane & 15;

  __shared__ __align__(16) short Ksm[2][64 * 128];   // XOR-swizzled (chunk ^= row&7)
  __shared__ __align__(16) short Vsm[2][64 * 128];   // subtiled [k/4][d/16][4][16]
  __shared__ __align__(16) short Psm[8][16 * 72];

  const float scale = 0.08838834764831845f;

  const int qrow = qt * 128 + wave * 16 + llo;
  const short* qbase = qkv + (size_t)qrow * QKV_LD + (kvh * 6 + g) * HD;
  short8 qf[4];
#pragma unroll
  for (int kk = 0; kk < 4; kk++) qf[kk] = *(const short8*)(qbase + kk * 32 + lhi * 8);

  f32x4 o[8] = {};
  float mrow[4], lrow[4];
#pragma unroll
  for (int r = 0; r < 4; r++) { mrow[r] = -1e30f; lrow[r] = 0.f; }

  const short* Kg = qkv + (kvh * 6 + 4) * HD;
  const short* Vg = qkv + (kvh * 6 + 5) * HD;

  auto STAGE_K = [&](int t, int buf) {
#pragma unroll
    for (int c = 0; c < 2; c++) {
      const int call = wave * 2 + c;                  // 16 calls x 1KB = 16KB
      const int row = call * 4 + lhi;
      const int sc = llo ^ (row & 7);
      __builtin_amdgcn_global_load_lds(
          (const __attribute__((address_space(1))) uint32_t*)(Kg + (size_t)(t * 64 + row) * QKV_LD + sc * 8),
          (__attribute__((address_space(3))) uint32_t*)(&Ksm[buf][0] + call * 512), 16, 0, 0);
    }
  };
  short8 vreg[2];
  auto LOAD_V = [&](int t) {
#pragma unroll
    for (int c = 0; c < 2; c++) {
      const int idx = c * 512 + tid;
      const int vr = idx >> 4;
      vreg[c] = *(const short8*)(Vg + (size_t)(t * 64 + vr) * QKV_LD + (idx & 15) * 8);
    }
  };
  auto WRITE_V = [&](int buf) {
#pragma unroll
    for (int c = 0; c < 2; c++) {
      const int idx = c * 512 + tid;
      const int vr = idx >> 4, vc = idx & 15;
      *(short8*)(&Vsm[buf][0] + ((vr >> 2) * 8 + (vc >> 1)) * 64 + (vr & 3) * 16 + (vc & 1) * 8) = vreg[c];
    }
  };

  const uint32_t vlane0 = (uint32_t)(uintptr_t)(__attribute__((address_space(3))) short*)(&Vsm[0][0])
                          + (uint32_t)(lhi * 2048 + llo * 8);

  STAGE_K(0, 0);
  LOAD_V(0);
  asm volatile("s_waitcnt vmcnt(0)" ::: "memory");
  WRITE_V(0);
  __syncthreads();

  const int ntiles = 2 * qt + 2;
  const int qpos0 = qt * 128 + wave * 16 + lhi * 4;   // + r
  for (int t = 0; t < ntiles; t++) {
    const int cur = t & 1, nxt = cur ^ 1;
    const bool pf = (t + 1 < ntiles);
    if (pf) { STAGE_K(t + 1, nxt); LOAD_V(t + 1); }

    const short* Kc = &Ksm[cur][0];
    f32x4 s[4] = {};
#pragma unroll
    for (int n = 0; n < 4; n++) {
#pragma unroll
      for (int kk = 0; kk < 4; kk++) {
        const int krow = n * 16 + llo;
        const int ch = (kk * 4 + lhi) ^ (krow & 7);
        short8 kf = *(const short8*)(Kc + krow * 128 + ch * 8);
        s[n] = __builtin_amdgcn_mfma_f32_16x16x32_bf16(qf[kk], kf, s[n], 0, 0, 0);
      }
    }

    float sv[4][4];
    const bool diag = (t >= 2 * qt);                  // only top 2 tiles cross the diagonal
#pragma unroll
    for (int n = 0; n < 4; n++)
#pragma unroll
      for (int r = 0; r < 4; r++) {
        float x = s[n][r] * scale;
        if (diag && (t * 64 + n * 16 + llo > qpos0 + r)) x = -1e30f;
        sv[n][r] = x;
      }

    float rm4[4];
#pragma unroll
    for (int r = 0; r < 4; r++) {
      float rm = fmaxf(fmaxf(sv[0][r], sv[1][r]), fmaxf(sv[2][r], sv[3][r]));
#pragma unroll
      for (int msk = 1; msk < 16; msk <<= 1) rm = fmaxf(rm, __shfl_xor(rm, msk));
      rm4[r] = rm;
    }
    bool need = false;
#pragma unroll
    for (int r = 0; r < 4; r++) need = need || (rm4[r] > mrow[r] + 8.0f);
    if (__any(need)) {
#pragma unroll
      for (int r = 0; r < 4; r++) {
        const float mnew = fmaxf(mrow[r], rm4[r]);
        const float a = __expf(mrow[r] - mnew);
        mrow[r] = mnew;
        lrow[r] *= a;
#pragma unroll
        for (int nn = 0; nn < 8; nn++) o[nn][r] *= a;
      }
    }
#pragma unroll
    for (int r = 0; r < 4; r++) {
      float rs = 0.f;
#pragma unroll
      for (int n = 0; n < 4; n++) {
        float p = __expf(sv[n][r] - mrow[r]);
        sv[n][r] = p;
        rs += p;
      }
#pragma unroll
      for (int msk = 1; msk < 16; msk <<= 1) rs += __shfl_xor(rs, msk);
      lrow[r] += rs;
    }

    short* P = &Psm[wave][0];
#pragma unroll
    for (int n = 0; n < 4; n++)
#pragma unroll
      for (int r = 0; r < 4; r++)
        P[(lhi * 4 + r) * 72 + n * 16 + llo] = f2bf(sv[n][r]);

    short8 pa0 = *(const short8*)(P + llo * 72 + lhi * 8);
    short8 pa1 = *(const short8*)(P + llo * 72 + 32 + lhi * 8);
    const uint32_t vlane = vlane0 + (uint32_t)(cur * 16384);
#pragma unroll
    for (int ks = 0; ks < 2; ks++) {
      uint2v vr_[8][2];
#pragma unroll
      for (int nn = 0; nn < 8; nn++)
#pragma unroll
        for (int hh = 0; hh < 2; hh++) {
          uint32_t a = vlane + (uint32_t)(ks * 8192 + hh * 1024 + nn * 128);
          asm volatile("ds_read_b64_tr_b16 %0, %1" : "=v"(vr_[nn][hh]) : "v"(a));
        }
      asm volatile("s_waitcnt lgkmcnt(0)" ::: "memory");
      __builtin_amdgcn_sched_barrier(0);
      const short8 pa = ks ? pa1 : pa0;
#pragma unroll
      for (int nn = 0; nn < 8; nn++) {
        int4v tv;
        tv[0] = (int)vr_[nn][0][0]; tv[1] = (int)vr_[nn][0][1];
        tv[2] = (int)vr_[nn][1][0]; tv[3] = (int)vr_[nn][1][1];
        o[nn] = __builtin_amdgcn_mfma_f32_16x16x32_bf16(pa, __builtin_bit_cast(short8, tv), o[nn], 0, 0, 0);
      }
    }

    if (pf) {
      asm volatile("s_waitcnt vmcnt(0)" ::: "memory");
      __syncthreads();
      WRITE_V(nxt);
      __syncthreads();
    }
  }

#pragma unroll
  for (int nn = 0; nn < 8; nn++)
#pragma unroll
    for (int r = 0; r < 4; r++) {
      const size_t row = qt * 128 + wave * 16 + lhi * 4 + r;
      const size_t col = (size_t)h * HD + nn * 16 + llo;
      aout[row * OUT_LD + col] = f2bf(o[nn][r] / lrow[r]);
    }
}

// ---------------- launch ----------------
extern "C" void kernel_launch(void* const* d_in, const int* in_sizes, int n_in,
                              void* d_out, int out_size, void* d_ws, size_t ws_size,
                              hipStream_t stream) {
  const float* tokens = (const float*)d_in[0];
  const float* wqkv   = (const float*)d_in[1];
  const float* wproj  = (const float*)d_in[2];
  float* out = (float*)d_out;

  short* tok_bf   = (short*)d_ws;
  short* wqkv_bf  = tok_bf   + (size_t)SEQ * HIDDEN;
  short* wproj_bf = wqkv_bf  + (size_t)QKV_LD * HIDDEN;
  short* qkv_bf   = wproj_bf + (size_t)HIDDEN * OUT_LD;
  short* attn_bf  = qkv_bf   + (size_t)SEQ * QKV_LD;

  cast_kernel<<<2048, 256, 0, stream>>>(tokens, tok_bf, SEQ * HIDDEN / 4);
  cast_kernel<<<2048, 256, 0, stream>>>(wqkv, wqkv_bf, QKV_LD * HIDDEN / 4);
  cast_kernel<<<2048, 256, 0, stream>>>(wproj, wproj_bf, HIDDEN * OUT_LD / 4);

  // QKV: 256x192 tiles -> 8 x 32 = 256 workgroups
  gemm256b<short, 3><<<256, 512, 0, stream>>>(tok_bf, wqkv_bf, qkv_bf, SEQ, QKV_LD, HIDDEN, QKV_LD / 192);

  attn_fwd<<<dim3(NHEADS, SEQ / 128), 512, 0, stream>>>(qkv_bf, attn_bf);

  // proj: 256x128 tiles -> 8 x 32 = 256 workgroups
  gemm256b<float, 2><<<256, 512, 0, stream>>>(attn_bf, wproj_bf, out, SEQ, OUT_LD, HIDDEN, OUT_LD / 128);
}

// Round 10
// 316.658 us; speedup vs baseline: 1.7222x; 1.0073x over previous
//
#include <hip/hip_runtime.h>
#include <hip/hip_bf16.h>
#include <stdint.h>

#define SEQ 2048
#define HIDDEN 4096
#define NHEADS 32
#define HD 128
#define QKV_LD 6144
#define OUT_LD 4096

typedef __attribute__((ext_vector_type(8))) short short8;
typedef __attribute__((ext_vector_type(4))) short short4v;
typedef __attribute__((ext_vector_type(4))) float f32x4;
typedef __attribute__((ext_vector_type(4))) int int4v;
typedef __attribute__((ext_vector_type(2))) unsigned int uint2v;
typedef __attribute__((ext_vector_type(4))) float float4v;

__device__ __forceinline__ short f2bf(float f) {
  uint32_t u = __builtin_bit_cast(uint32_t, f);
  u += 0x7fff + ((u >> 16) & 1);   // RNE
  return (short)(u >> 16);
}

// ---------------- cast fp32 -> bf16 ----------------
__global__ void cast_kernel(const float* __restrict__ in, short* __restrict__ out, int n4) {
  int stride = gridDim.x * blockDim.x;
  for (int i = blockIdx.x * blockDim.x + threadIdx.x; i < n4; i += stride) {
    float4v v = ((const float4v*)in)[i];
    short4v o;
    o[0] = f2bf(v[0]); o[1] = f2bf(v[1]); o[2] = f2bf(v[2]); o[3] = f2bf(v[3]);
    ((short4v*)out)[i] = o;
  }
}

// ======== 256 x (64*NBF) GEMM, 2-barrier K-tile: C = A[M][K] * B[N][K]^T ========
// 512 thr = 8 waves (2M x 4N). BK=64, double-buffered LDS, chunk^=row&7 swizzle.
// XCD map: each XCD owns NT/8 nt-columns x all 8 mt (mt-fast) -> B panel
// (1.5MB/1MB) stays L2-resident across 8 blocks; only A streams from L3.
template <typename OT, int NBF>
__global__ __launch_bounds__(512, 2) void gemm256b(const short* __restrict__ A,
                                                   const short* __restrict__ B,
                                                   OT* __restrict__ C,
                                                   int M, int N, int K, int NT) {
  __shared__ __align__(16) short lds[32768 + NBF * 8192];  // A: 2x16384, B: 2x NBF*4096
  const int tid = threadIdx.x;
  const int w = tid >> 6, lane = tid & 63;
  const int wr = w >> 2, wc = w & 3;
  const int llo = lane & 15, lhi = lane >> 4;

  // XCD-local B-resident mapping (requires NT%8==0, M/256==8, nwg==256)
  const int xcd = (int)blockIdx.x & 7;
  const int i = (int)blockIdx.x >> 3;        // 0..31 within XCD
  const int nt = xcd * (NT >> 3) + (i >> 3); // NT/8 cols per XCD
  const int mt = i & 7;                      // mt-fast: B panel reused in L2
  const size_t arow0 = (size_t)mt * 256, brow0 = (size_t)nt * (NBF * 64);
  const short* Ab = A + arow0 * K;
  const short* Bb = B + brow0 * K;

  f32x4 acc[8][NBF] = {};

  auto STAGE_A = [&](int kt, int j) {
    const int bufd = kt & 1;
    const int r0 = (j << 6) + (w << 3);
    const int row = r0 + (lane >> 3);
    const short* src = Ab + (size_t)row * K + (kt << 6) + (((lane & 7) ^ (row & 7)) << 3);
    short* dst = lds + (bufd << 14) + r0 * 64;
    __builtin_amdgcn_global_load_lds(
        (const __attribute__((address_space(1))) uint32_t*)src,
        (__attribute__((address_space(3))) uint32_t*)dst, 16, 0, 0);
  };
  auto STAGE_B = [&](int kt, int j) {
    const int bufd = kt & 1;
    const int r0 = (j << 6) + (w << 3);
    const int row = r0 + (lane >> 3);
    const short* src = Bb + (size_t)row * K + (kt << 6) + (((lane & 7) ^ (row & 7)) << 3);
    short* dst = lds + 32768 + bufd * (NBF << 12) + r0 * 64;
    __builtin_amdgcn_global_load_lds(
        (const __attribute__((address_space(1))) uint32_t*)src,
        (__attribute__((address_space(3))) uint32_t*)dst, 16, 0, 0);
  };
  auto STAGE = [&](int kt) {
#pragma unroll
    for (int j = 0; j < 4; j++) STAGE_A(kt, j);
#pragma unroll
    for (int j = 0; j < NBF; j++) STAGE_B(kt, j);
  };

  auto LDA = [&](int bufd, int m, int kk) -> short8 {
    const int row = (wr << 7) + (m << 4) + llo;
    const int ch = ((kk << 2) + lhi) ^ (row & 7);
    return *(const short8*)(lds + (bufd << 14) + row * 64 + (ch << 3));
  };
  auto LDB = [&](int bufd, int n, int kk) -> short8 {
    const int row = wc * (NBF << 4) + (n << 4) + llo;
    const int ch = ((kk << 2) + lhi) ^ (row & 7);
    return *(const short8*)(lds + 32768 + bufd * (NBF << 12) + row * 64 + (ch << 3));
  };

  // ---- prologue: stage tiles 0 and 1, gate tile 0 ----
  STAGE(0);
  STAGE(1);
  if constexpr (NBF == 3) asm volatile("s_waitcnt vmcnt(7)" ::: "memory");
  else                    asm volatile("s_waitcnt vmcnt(6)" ::: "memory");
  __builtin_amdgcn_s_barrier();

  const int NKT = K >> 6;
  for (int kt = 0; kt < NKT; ++kt) {
    const int bufd = kt & 1;
    short8 b_[NBF][2];
#pragma unroll
    for (int n = 0; n < NBF; n++) { b_[n][0] = LDB(bufd, n, 0); b_[n][1] = LDB(bufd, n, 1); }
#pragma unroll
    for (int m = 0; m < 8; m++) {
      short8 a0 = LDA(bufd, m, 0);
      short8 a1 = LDA(bufd, m, 1);
#pragma unroll
      for (int n = 0; n < NBF; n++) {
        acc[m][n] = __builtin_amdgcn_mfma_f32_16x16x32_bf16(a0, b_[n][0], acc[m][n], 0, 0, 0);
        acc[m][n] = __builtin_amdgcn_mfma_f32_16x16x32_bf16(a1, b_[n][1], acc[m][n], 0, 0, 0);
      }
    }
    asm volatile("s_waitcnt lgkmcnt(0)" ::: "memory");
    __builtin_amdgcn_s_barrier();            // all waves done reading bufd
    if (kt + 2 < NKT) STAGE(kt + 2);         // refill this buffer
    if (kt + 1 < NKT) {
      if (kt + 2 < NKT) {
        if constexpr (NBF == 3) asm volatile("s_waitcnt vmcnt(7)" ::: "memory");
        else                    asm volatile("s_waitcnt vmcnt(6)" ::: "memory");
      } else {
        asm volatile("s_waitcnt vmcnt(0)" ::: "memory");
      }
      __builtin_amdgcn_s_barrier();          // next tile's data visible
    }
  }

  // ---- epilogue ----
#pragma unroll
  for (int m = 0; m < 8; m++)
#pragma unroll
    for (int n = 0; n < NBF; n++)
#pragma unroll
      for (int r = 0; r < 4; r++) {
        const size_t row = arow0 + (wr << 7) + (m << 4) + (lhi << 2) + r;
        const size_t col = brow0 + wc * (NBF << 4) + (n << 4) + llo;
        const float v = acc[m][n][r];
        if constexpr (sizeof(OT) == 2) C[row * N + col] = f2bf(v);
        else                           C[row * N + col] = v;
      }
}

// ---------------- flash attention, causal GQA ----------------
// grid: (NHEADS, SEQ/128); block 512 = 8 waves x 16 q-rows; qt reversed.
// Double-buffered K/V prefetch; defer-max (T13); log2-domain softmax;
// tr-reads via single base + offset immediates.
__global__ __launch_bounds__(512) void attn_fwd(const short* __restrict__ qkv,
                                                short* __restrict__ aout) {
  const int qt = gridDim.y - 1 - blockIdx.y;          // heavy blocks first
  const int h = blockIdx.x;
  const int kvh = h >> 2, g = h & 3;
  const int tid = threadIdx.x;
  const int wave = tid >> 6, lane = tid & 63;
  const int lhi = lane >> 4, llo = lane & 15;

  __shared__ __align__(16) short Ksm[2][64 * 128];   // XOR-swizzled (chunk ^= row&7)
  __shared__ __align__(16) short Vsm[2][64 * 128];   // subtiled [k/4][d/16][4][16]
  __shared__ __align__(16) short Psm[8][16 * 72];

  // log2-domain: S2 = S * (1/sqrt(128) * log2(e)); P = exp2(S2 - m2)
  const float scale2 = 0.08838834764831845f * 1.4426950408889634f;

  const int qrow = qt * 128 + wave * 16 + llo;
  const short* qbase = qkv + (size_t)qrow * QKV_LD + (kvh * 6 + g) * HD;
  short8 qf[4];
#pragma unroll
  for (int kk = 0; kk < 4; kk++) qf[kk] = *(const short8*)(qbase + kk * 32 + lhi * 8);

  f32x4 o[8] = {};
  float mrow[4], lrow[4];
#pragma unroll
  for (int r = 0; r < 4; r++) { mrow[r] = -1e30f; lrow[r] = 0.f; }

  const short* Kg = qkv + (kvh * 6 + 4) * HD;
  const short* Vg = qkv + (kvh * 6 + 5) * HD;

  auto STAGE_K = [&](int t, int buf) {
#pragma unroll
    for (int c = 0; c < 2; c++) {
      const int call = wave * 2 + c;                  // 16 calls x 1KB = 16KB
      const int row = call * 4 + lhi;
      const int sc = llo ^ (row & 7);
      __builtin_amdgcn_global_load_lds(
          (const __attribute__((address_space(1))) uint32_t*)(Kg + (size_t)(t * 64 + row) * QKV_LD + sc * 8),
          (__attribute__((address_space(3))) uint32_t*)(&Ksm[buf][0] + call * 512), 16, 0, 0);
    }
  };
  short8 vreg[2];
  auto LOAD_V = [&](int t) {
#pragma unroll
    for (int c = 0; c < 2; c++) {
      const int idx = c * 512 + tid;
      const int vr = idx >> 4;
      vreg[c] = *(const short8*)(Vg + (size_t)(t * 64 + vr) * QKV_LD + (idx & 15) * 8);
    }
  };
  auto WRITE_V = [&](int buf) {
#pragma unroll
    for (int c = 0; c < 2; c++) {
      const int idx = c * 512 + tid;
      const int vr = idx >> 4, vc = idx & 15;
      *(short8*)(&Vsm[buf][0] + ((vr >> 2) * 8 + (vc >> 1)) * 64 + (vr & 3) * 16 + (vc & 1) * 8) = vreg[c];
    }
  };

  const uint32_t vlane0 = (uint32_t)(uintptr_t)(__attribute__((address_space(3))) short*)(&Vsm[0][0])
                          + (uint32_t)(lhi * 2048 + llo * 8);

  STAGE_K(0, 0);
  LOAD_V(0);
  asm volatile("s_waitcnt vmcnt(0)" ::: "memory");
  WRITE_V(0);
  __syncthreads();

  const int ntiles = 2 * qt + 2;
  const int qpos0 = qt * 128 + wave * 16 + lhi * 4;   // + r
  for (int t = 0; t < ntiles; t++) {
    const int cur = t & 1, nxt = cur ^ 1;
    const bool pf = (t + 1 < ntiles);
    if (pf) { STAGE_K(t + 1, nxt); LOAD_V(t + 1); }

    const short* Kc = &Ksm[cur][0];
    f32x4 s[4] = {};
#pragma unroll
    for (int n = 0; n < 4; n++) {
#pragma unroll
      for (int kk = 0; kk < 4; kk++) {
        const int krow = n * 16 + llo;
        const int ch = (kk * 4 + lhi) ^ (krow & 7);
        short8 kf = *(const short8*)(Kc + krow * 128 + ch * 8);
        s[n] = __builtin_amdgcn_mfma_f32_16x16x32_bf16(qf[kk], kf, s[n], 0, 0, 0);
      }
    }

    float sv[4][4];
    if (t >= 2 * qt) {   // diagonal tiles: apply causal mask (wave-uniform branch)
#pragma unroll
      for (int n = 0; n < 4; n++)
#pragma unroll
        for (int r = 0; r < 4; r++) {
          float x = s[n][r] * scale2;
          if (t * 64 + n * 16 + llo > qpos0 + r) x = -1e30f;
          sv[n][r] = x;
        }
    } else {
#pragma unroll
      for (int n = 0; n < 4; n++)
#pragma unroll
        for (int r = 0; r < 4; r++) sv[n][r] = s[n][r] * scale2;
    }

    float rm4[4];
#pragma unroll
    for (int r = 0; r < 4; r++) {
      float rm = fmaxf(fmaxf(sv[0][r], sv[1][r]), fmaxf(sv[2][r], sv[3][r]));
#pragma unroll
      for (int msk = 1; msk < 16; msk <<= 1) rm = fmaxf(rm, __shfl_xor(rm, msk));
      rm4[r] = rm;
    }
    bool need = false;
#pragma unroll
    for (int r = 0; r < 4; r++) need = need || (rm4[r] > mrow[r] + 8.0f);
    if (__any(need)) {
#pragma unroll
      for (int r = 0; r < 4; r++) {
        const float mnew = fmaxf(mrow[r], rm4[r]);
        const float a = exp2f(mrow[r] - mnew);
        mrow[r] = mnew;
        lrow[r] *= a;
#pragma unroll
        for (int nn = 0; nn < 8; nn++) o[nn][r] *= a;
      }
    }
#pragma unroll
    for (int r = 0; r < 4; r++) {
      float rs = 0.f;
#pragma unroll
      for (int n = 0; n < 4; n++) {
        float p = exp2f(sv[n][r] - mrow[r]);
        sv[n][r] = p;
        rs += p;
      }
#pragma unroll
      for (int msk = 1; msk < 16; msk <<= 1) rs += __shfl_xor(rs, msk);
      lrow[r] += rs;
    }

    short* P = &Psm[wave][0];
#pragma unroll
    for (int n = 0; n < 4; n++)
#pragma unroll
      for (int r = 0; r < 4; r++)
        P[(lhi * 4 + r) * 72 + n * 16 + llo] = f2bf(sv[n][r]);

    short8 pa0 = *(const short8*)(P + llo * 72 + lhi * 8);
    short8 pa1 = *(const short8*)(P + llo * 72 + 32 + lhi * 8);
    const uint32_t vbase = vlane0 + (uint32_t)(cur * 16384);
#pragma unroll
    for (int ks = 0; ks < 2; ks++) {
      uint2v vr_[8][2];
#pragma unroll
      for (int nn = 0; nn < 8; nn++)
#pragma unroll
        for (int hh = 0; hh < 2; hh++) {
          asm volatile("ds_read_b64_tr_b16 %0, %1 offset:%2"
                       : "=v"(vr_[nn][hh])
                       : "v"(vbase), "i"(ks * 8192 + hh * 1024 + nn * 128));
        }
      asm volatile("s_waitcnt lgkmcnt(0)" ::: "memory");
      __builtin_amdgcn_sched_barrier(0);
      const short8 pa = ks ? pa1 : pa0;
#pragma unroll
      for (int nn = 0; nn < 8; nn++) {
        int4v tv;
        tv[0] = (int)vr_[nn][0][0]; tv[1] = (int)vr_[nn][0][1];
        tv[2] = (int)vr_[nn][1][0]; tv[3] = (int)vr_[nn][1][1];
        o[nn] = __builtin_amdgcn_mfma_f32_16x16x32_bf16(pa, __builtin_bit_cast(short8, tv), o[nn], 0, 0, 0);
      }
    }

    if (pf) {
      asm volatile("s_waitcnt vmcnt(0)" ::: "memory");
      __syncthreads();
      WRITE_V(nxt);
      __syncthreads();
    }
  }

#pragma unroll
  for (int nn = 0; nn < 8; nn++)
#pragma unroll
    for (int r = 0; r < 4; r++) {
      const size_t row = qt * 128 + wave * 16 + lhi * 4 + r;
      const size_t col = (size_t)h * HD + nn * 16 + llo;
      aout[row * OUT_LD + col] = f2bf(o[nn][r] / lrow[r]);
    }
}

// ---------------- launch ----------------
extern "C" void kernel_launch(void* const* d_in, const int* in_sizes, int n_in,
                              void* d_out, int out_size, void* d_ws, size_t ws_size,
                              hipStream_t stream) {
  const float* tokens = (const float*)d_in[0];
  const float* wqkv   = (const float*)d_in[1];
  const float* wproj  = (const float*)d_in[2];
  float* out = (float*)d_out;

  short* tok_bf   = (short*)d_ws;
  short* wqkv_bf  = tok_bf   + (size_t)SEQ * HIDDEN;
  short* wproj_bf = wqkv_bf  + (size_t)QKV_LD * HIDDEN;
  short* qkv_bf   = wproj_bf + (size_t)HIDDEN * OUT_LD;
  short* attn_bf  = qkv_bf   + (size_t)SEQ * QKV_LD;

  cast_kernel<<<2048, 256, 0, stream>>>(tokens, tok_bf, SEQ * HIDDEN / 4);
  cast_kernel<<<2048, 256, 0, stream>>>(wqkv, wqkv_bf, QKV_LD * HIDDEN / 4);
  cast_kernel<<<2048, 256, 0, stream>>>(wproj, wproj_bf, HIDDEN * OUT_LD / 4);

  // QKV: 256x192 tiles -> 256 workgroups; NT=32 nt-cols, 4 per XCD
  gemm256b<short, 3><<<256, 512, 0, stream>>>(tok_bf, wqkv_bf, qkv_bf, SEQ, QKV_LD, HIDDEN, QKV_LD / 192);

  attn_fwd<<<dim3(NHEADS, SEQ / 128), 512, 0, stream>>>(qkv_bf, attn_bf);

  // proj: 256x128 tiles -> 256 workgroups; NT=32
  gemm256b<float, 2><<<256, 512, 0, stream>>>(attn_bf, wproj_bf, out, SEQ, OUT_LD, HIDDEN, OUT_LD / 128);
}